// Round 12
// baseline (482.121 us; speedup 1.0000x reference)
//
#include <hip/hip_runtime.h>
#include <hip/hip_bf16.h>

using bf16 = __hip_bfloat16;

#define DEV_INLINE __device__ __forceinline__

// Problem constants
constexpr int B_  = 4;
constexpr int LQ  = 3000;
constexpr int LK  = 750;
constexpr int NH_ = 4;
constexpr float EPSF = 1e-6f;

// LDS pitch in uint2 elements per d4-row (>=750, odd)
constexpr int PITCH = 753;

// Workspace layout (fp32 elements).
constexpr size_t WS_KV = 0;        // 6 x B*LK*64 = 1,152,000
constexpr size_t WS_XB = 1152000;  // B*LQ*64 = 768,000 (unused now)
constexpr size_t WS_QP = 1920000;  // 768,000
constexpr size_t WS_AO = 2688000;  // 768,000
constexpr size_t WS_QN = 3456000;  // 768,000
constexpr size_t WS_SG = 4224000;  // 768,000

typedef _Float16 half2_t __attribute__((ext_vector_type(2)));

DEV_INLINE float sigmoidf(float x) { return 1.f / (1.f + __expf(-x)); }

DEV_INLINE unsigned int packh2(float a, float b) {
  half2_t h = { (_Float16)a, (_Float16)b };
  unsigned int u; __builtin_memcpy(&u, &h, 4); return u;
}
DEV_INLINE half2_t u2h(unsigned int u) {
  half2_t h; __builtin_memcpy(&h, &u, 4); return h;
}
// one v_dot2_f32_f16: acc + k.x*q.x + k.y*q.y
DEV_INLINE float dot2(unsigned int kw, half2_t qh, float acc) {
  return __builtin_amdgcn_fdot2(u2h(kw), qh, acc, false);
}

DEV_INLINE unsigned int f2sort(float f) {
  int ib = __float_as_int(f);
  return (unsigned int)(ib ^ ((ib >> 31) | 0x80000000));
}

DEV_INLINE unsigned int bcastu(unsigned int v) {
  return (unsigned int)__builtin_amdgcn_readfirstlane((int)v);
}

DEV_INLINE float row_ln(float v, float g, float b) {
  float s1 = v, s2 = v * v;
  #pragma unroll
  for (int off = 32; off > 0; off >>= 1) {
    s1 += __shfl_xor(s1, off);
    s2 += __shfl_xor(s2, off);
  }
  const float m   = s1 * (1.f / 64.f);
  const float var = s2 * (1.f / 64.f) - m * m;
  return (v - m) * rsqrtf(var + EPSF) * g + b;
}

// ---------------------------------------------------------------------------
// Merged projections: y<6 -> K/V of enc (188 blocks used); y==6 -> q-proj
// (750 blocks). 16 rows/block.
// ---------------------------------------------------------------------------
__global__ __launch_bounds__(256) void kvq_proj_kernel(
    const float* __restrict__ enc, const float* __restrict__ q,
    const float* __restrict__ calWq,
    const float* __restrict__ calWk, const float* __restrict__ calWv,
    const float* __restrict__ mWk, const float* __restrict__ mWv,
    float* __restrict__ kv, float* __restrict__ qp)
{
  const int y = blockIdx.y;
  if (y < 6 && blockIdx.x >= 188) return;
  __shared__ float Wl[64 * 65];
  __shared__ float xs[16][64];
  const int t = threadIdx.x, rr = t >> 6, cc = t & 63;
  const float* W;
  const float* src;
  float* dst;
  float scale = 1.f;
  int nrows = 3000;
  switch (y) {
    case 0: W = calWk; src = enc; dst = kv;               break;
    case 1: W = calWv; src = enc; dst = kv + 192000;      break;
    case 2: W = mWk;        src = enc; dst = kv + 384000; break;
    case 3: W = mWv;        src = enc; dst = kv + 576000; break;
    case 4: W = mWk + 4096; src = enc; dst = kv + 768000; break;
    case 5: W = mWv + 4096; src = enc; dst = kv + 960000; break;
    default: W = calWq; src = q; dst = qp; scale = 0.25f; nrows = 12000; break;
  }
  for (int i = t; i < 4096; i += 256) Wl[(i >> 6) * 65 + (i & 63)] = W[i];
  const int base = blockIdx.x * 16;
  for (int i = t; i < 1024; i += 256) {
    const int grow = base + (i >> 6);
    xs[i >> 6][i & 63] = (grow < nrows) ? src[(size_t)grow * 64 + (i & 63)] : 0.f;
  }
  __syncthreads();
  #pragma unroll
  for (int p = 0; p < 4; ++p) {
    const int row = p * 4 + rr;
    const int grow = base + row;
    float acc = 0.f;
    #pragma unroll
    for (int c = 0; c < 64; ++c) acc = fmaf(xs[row][c], Wl[c * 65 + cc], acc);
    if (grow < nrows) dst[(size_t)grow * 64 + cc] = acc * scale;
  }
}

// ---------------------------------------------------------------------------
// CROSS attention (round-10 verified: 94.5 us). grid (375, NH, B), block 256.
// K,V both staged upfront as packed-f16 uint2; QK^T via v_dot2_f32_f16;
// PV via fma_mix; barrier-free per-wave swizzled PV reduce.
// LDS 52,288 B -> 3 blocks/CU. NOTE (r11): shrinking LDS to 28 KB with phased
// K->V reuse REGRESSED (+5 us) — residency is not capacity-limited here.
// ---------------------------------------------------------------------------
__global__ __launch_bounds__(256) void cross_attn_kernel(
    const float* __restrict__ qp, const float* __restrict__ kp,
    const float* __restrict__ vp, float* __restrict__ ao)
{
  extern __shared__ char smem[];
  uint2* KT2 = (uint2*)smem;                        // [4][PITCH]
  uint2* VT2 = KT2 + 4 * PITCH;                     // [4][PITCH]
  float* red = (float*)(smem + 2 * 4 * PITCH * 8);  // [4 waves][256]

  const int t = threadIdx.x;
  const int h = blockIdx.y, b = blockIdx.z;
  const float* kslab = kp + (size_t)(b * LK) * 64 + h * 16;
  const float* vslab = vp + (size_t)(b * LK) * 64 + h * 16;

  for (int k = t; k < LK; k += 256) {
    const float4* ks = (const float4*)(kslab + (size_t)k * 64);
    const float4* vs = (const float4*)(vslab + (size_t)k * 64);
    #pragma unroll
    for (int q4 = 0; q4 < 4; ++q4) {
      float4 a = ks[q4], v = vs[q4];
      KT2[q4 * PITCH + k] = make_uint2(packh2(a.x, a.y), packh2(a.z, a.w));
      VT2[q4 * PITCH + k] = make_uint2(packh2(v.x, v.y), packh2(v.z, v.w));
    }
  }
  __syncthreads();

  const int wave = t >> 6, lane = t & 63;
  const int r0 = blockIdx.x * 8 + wave * 2;
  const float* qrow = qp + ((size_t)(b * LQ + r0)) * 64 + h * 16;
  half2_t qh0[8], qh1[8];
  #pragma unroll
  for (int i = 0; i < 8; ++i) {
    qh0[i] = u2h(packh2(qrow[2 * i], qrow[2 * i + 1]));
    qh1[i] = u2h(packh2(qrow[64 + 2 * i], qrow[64 + 2 * i + 1]));
  }

  float lg0[12], lg1[12];
  #pragma unroll
  for (int tt = 0; tt < 12; ++tt) {
    const int k = lane + (tt << 6);
    if (tt < 11 || k < LK) {
      float a0 = 0.f, a1 = 0.f;
      #pragma unroll
      for (int d4 = 0; d4 < 4; ++d4) {
        const uint2 w = KT2[d4 * PITCH + k];
        a0 = dot2(w.x, qh0[2 * d4], a0); a0 = dot2(w.y, qh0[2 * d4 + 1], a0);
        a1 = dot2(w.x, qh1[2 * d4], a1); a1 = dot2(w.y, qh1[2 * d4 + 1], a1);
      }
      lg0[tt] = a0; lg1[tt] = a1;
    } else {
      lg0[tt] = -1e30f; lg1[tt] = -1e30f;
    }
  }

  float m0 = lg0[0], m1 = lg1[0];
  #pragma unroll
  for (int tt = 1; tt < 12; ++tt) { m0 = fmaxf(m0, lg0[tt]); m1 = fmaxf(m1, lg1[tt]); }
  #pragma unroll
  for (int off = 32; off > 0; off >>= 1) {
    m0 = fmaxf(m0, __shfl_xor(m0, off));
    m1 = fmaxf(m1, __shfl_xor(m1, off));
  }
  float s0 = 0.f, s1 = 0.f;
  #pragma unroll
  for (int tt = 0; tt < 12; ++tt) {
    lg0[tt] = __expf(lg0[tt] - m0); s0 += lg0[tt];
    lg1[tt] = __expf(lg1[tt] - m1); s1 += lg1[tt];
  }
  #pragma unroll
  for (int off = 32; off > 0; off >>= 1) {
    s0 += __shfl_xor(s0, off);
    s1 += __shfl_xor(s1, off);
  }
  const float inv0 = 1.f / s0, inv1 = 1.f / s1;

  float* red_w = red + wave * 256;
  const int dd = lane & 3, g = lane >> 2;
  float* aor0 = ao + ((size_t)(b * LQ + r0)) * 64 + h * 16;
  float* aor1 = aor0 + 64;

  #pragma unroll
  for (int c = 0; c < 4; ++c) {
    float o0[4] = {0.f, 0.f, 0.f, 0.f}, o1[4] = {0.f, 0.f, 0.f, 0.f};
    #pragma unroll
    for (int tt = 0; tt < 12; ++tt) {
      const int k = lane + (tt << 6);
      if (tt < 11 || k < LK) {
        const float w0 = lg0[tt], w1 = lg1[tt];
        const uint2 w = VT2[c * PITCH + k];
        const half2_t va = u2h(w.x), vb = u2h(w.y);
        // (float)h folds into v_fma_mix_f32
        o0[0] = fmaf(w0, (float)va.x, o0[0]); o0[1] = fmaf(w0, (float)va.y, o0[1]);
        o0[2] = fmaf(w0, (float)vb.x, o0[2]); o0[3] = fmaf(w0, (float)vb.y, o0[3]);
        o1[0] = fmaf(w1, (float)va.x, o1[0]); o1[1] = fmaf(w1, (float)va.y, o1[1]);
        o1[2] = fmaf(w1, (float)vb.x, o1[2]); o1[3] = fmaf(w1, (float)vb.y, o1[3]);
      }
    }
    #pragma unroll
    for (int d = 0; d < 4; ++d) red_w[d * 64 + ((lane + 16 * d) & 63)] = o0[d];
    float a = 0.f;
    #pragma unroll
    for (int j = 0; j < 4; ++j)
      a += red_w[dd * 64 + ((g + 16 * j + 16 * dd) & 63)];
    #pragma unroll
    for (int off = 4; off <= 32; off <<= 1) a += __shfl_xor(a, off);
    if (g == 0) aor0[c * 4 + dd] = a * inv0;
    #pragma unroll
    for (int d = 0; d < 4; ++d) red_w[d * 64 + ((lane + 16 * d) & 63)] = o1[d];
    float a1r = 0.f;
    #pragma unroll
    for (int j = 0; j < 4; ++j)
      a1r += red_w[dd * 64 + ((g + 16 * j + 16 * dd) & 63)];
    #pragma unroll
    for (int off = 4; off <= 32; off <<= 1) a1r += __shfl_xor(a1r, off);
    if (g == 1) aor1[c * 4 + dd] = a1r * inv1;
  }
}

// ---------------------------------------------------------------------------
// AWG attention. grid (375, NH, B), block 256. K packed-f16 uint2 in LDS;
// logits via v_dot2_f32_f16 (recompute path bit-identical). Exact-on-f16K
// top-16 via 3-stage ballot select; V gathered from L2.
// LDS: 24,096 + 1,024 + 768 + 384 = 26,272 B -> 6 blocks/CU.
// ---------------------------------------------------------------------------
__global__ __launch_bounds__(256) void awg_attn_kernel(
    const float* __restrict__ qp, const float* __restrict__ kp,
    const float* __restrict__ vp, float* __restrict__ ao)
{
  extern __shared__ char smem[];
  uint2*          KT2   = (uint2*)smem;                              // [4][PITCH]
  unsigned short* candi = (unsigned short*)(smem + 4 * PITCH * 8);   // [4][2][64]
  float*          cw    = (float*)(smem + 4 * PITCH * 8 + 1024);     // [4][2][24]
  unsigned short* ciw   = (unsigned short*)(smem + 4 * PITCH * 8 + 1024 + 768);

  const int t = threadIdx.x;
  const int h = blockIdx.y, b = blockIdx.z;
  const float* kslab = kp + (size_t)(b * LK) * 64 + h * 16;

  for (int k = t; k < LK; k += 256) {
    const float4* ks = (const float4*)(kslab + (size_t)k * 64);
    #pragma unroll
    for (int q4 = 0; q4 < 4; ++q4) {
      float4 a = ks[q4];
      KT2[q4 * PITCH + k] = make_uint2(packh2(a.x, a.y), packh2(a.z, a.w));
    }
  }
  __syncthreads();

  const int wave = t >> 6, lane = t & 63;
  const unsigned long long below = (1ull << lane) - 1ull;
  unsigned short* ci0 = candi + wave * 128;
  unsigned short* ci1 = ci0 + 64;
  float* cw0 = cw + wave * 48;      float* cw1 = cw0 + 24;
  unsigned short* cio0 = ciw + wave * 48; unsigned short* cio1 = cio0 + 24;

  const int r0 = blockIdx.x * 8 + wave * 2;
  const float* qrow = qp + ((size_t)(b * LQ + r0)) * 64 + h * 16;
  unsigned int qw0[8], qw1[8];   // wave-uniform packed f16 q -> SGPRs
  #pragma unroll
  for (int i = 0; i < 8; ++i) {
    qw0[i] = bcastu(packh2(qrow[2 * i], qrow[2 * i + 1]));
    qw1[i] = bcastu(packh2(qrow[64 + 2 * i], qrow[64 + 2 * i + 1]));
  }

  float lg0[12], lg1[12];
  #pragma unroll
  for (int tt = 0; tt < 12; ++tt) {
    const int k = lane + (tt << 6);
    if (tt < 11 || k < LK) {
      float a0 = 0.f, a1 = 0.f;
      #pragma unroll
      for (int d4 = 0; d4 < 4; ++d4) {
        const uint2 w = KT2[d4 * PITCH + k];
        a0 = dot2(w.x, u2h(qw0[2 * d4]), a0); a0 = dot2(w.y, u2h(qw0[2 * d4 + 1]), a0);
        a1 = dot2(w.x, u2h(qw1[2 * d4]), a1); a1 = dot2(w.y, u2h(qw1[2 * d4 + 1]), a1);
      }
      lg0[tt] = a0; lg1[tt] = a1;
    } else {
      lg0[tt] = -3.0e38f; lg1[tt] = -3.0e38f;
    }
  }

  float fm0 = lg0[0], fm1 = lg1[0];
  #pragma unroll
  for (int tt = 1; tt < 12; ++tt) { fm0 = fmaxf(fm0, lg0[tt]); fm1 = fmaxf(fm1, lg1[tt]); }
  float M0 = fm0, M1 = fm1;
  #pragma unroll
  for (int off = 32; off > 0; off >>= 1) {
    M0 = fmaxf(M0, __shfl_xor(M0, off));
    M1 = fmaxf(M1, __shfl_xor(M1, off));
  }
  const unsigned int head0 = f2sort(fm0), head1 = f2sort(fm1);

  unsigned int L0 = 0u, L1 = 0u;
  #pragma unroll
  for (int bit = 31; bit >= 20; --bit) {
    const unsigned int c0 = L0 | (1u << bit);
    const unsigned int c1 = L1 | (1u << bit);
    if (__popcll(__ballot(head0 >= c0)) >= 16) L0 = c0;
    if (__popcll(__ballot(head1 >= c1)) >= 16) L1 = c1;
  }

  int base0 = 0, base1 = 0;
  #pragma unroll
  for (int tt = 0; tt < 12; ++tt) {
    const int k = lane + (tt << 6);
    const bool p0 = f2sort(lg0[tt]) >= L0;
    const bool p1 = f2sort(lg1[tt]) >= L1;
    const unsigned long long m0 = __ballot(p0);
    const unsigned long long m1 = __ballot(p1);
    if (p0) {
      const int pos = base0 + __popcll(m0 & below);
      if (pos < 64) ci0[pos] = (unsigned short)k;
    }
    if (p1) {
      const int pos = base1 + __popcll(m1 & below);
      if (pos < 64) ci1[pos] = (unsigned short)k;
    }
    base0 += __popcll(m0);
    base1 += __popcll(m1);
  }
  const int C0 = min(base0, 64), C1 = min(base1, 64);

  // recompute candidate logits (bit-identical dot2 order)
  const int k0 = (lane < C0) ? (int)ci0[lane] : 0;
  const int k1 = (lane < C1) ? (int)ci1[lane] : 0;
  float cv0 = 0.f, cv1 = 0.f;
  #pragma unroll
  for (int d4 = 0; d4 < 4; ++d4) {
    const uint2 wa = KT2[d4 * PITCH + k0];
    const uint2 wb = KT2[d4 * PITCH + k1];
    cv0 = dot2(wa.x, u2h(qw0[2 * d4]), cv0); cv0 = dot2(wa.y, u2h(qw0[2 * d4 + 1]), cv0);
    cv1 = dot2(wb.x, u2h(qw1[2 * d4]), cv1); cv1 = dot2(wb.y, u2h(qw1[2 * d4 + 1]), cv1);
  }
  const unsigned int cu0 = (lane < C0) ? f2sort(cv0) : 0u;
  const unsigned int cu1 = (lane < C1) ? f2sort(cv1) : 0u;

  unsigned int T0 = 0u, T1 = 0u;
  #pragma unroll
  for (int bit = 31; bit >= 0; --bit) {
    const unsigned int c0 = T0 | (1u << bit);
    const unsigned int c1 = T1 | (1u << bit);
    if (__popcll(__ballot(cu0 >= c0)) >= 16) T0 = c0;
    if (__popcll(__ballot(cu1 >= c1)) >= 16) T1 = c1;
  }

  const bool w0 = (lane < C0) && (cu0 >= T0);
  const bool w1 = (lane < C1) && (cu1 >= T1);
  const unsigned long long mw0 = __ballot(w0);
  const unsigned long long mw1 = __ballot(w1);
  const int cnt0 = min((int)__popcll(mw0), 24);
  const int cnt1 = min((int)__popcll(mw1), 24);
  if (w0) {
    const int pos = __popcll(mw0 & below);
    if (pos < 24) { cw0[pos] = cv0; cio0[pos] = (unsigned short)k0; }
  }
  if (w1) {
    const int pos = __popcll(mw1 & below);
    if (pos < 24) { cw1[pos] = cv1; cio1[pos] = (unsigned short)k1; }
  }

  const int dd = lane & 15;
  const int rsel = (lane >> 4) & 1;
  const int half = lane >> 5;
  const int cnt = rsel ? cnt1 : cnt0;
  const float* cwr = rsel ? cw1 : cw0;
  const unsigned short* cir = rsel ? cio1 : cio0;
  const float ref = rsel ? M1 : M0;
  const float* vbase = vp + (size_t)(b * LK) * 64 + h * 16 + dd;
  float acc = 0.f, Z = 0.f;
  for (int j = half; j < cnt; j += 2) {
    const float e = __expf(cwr[j] - ref);
    Z += e;
    acc = fmaf(e, vbase[(size_t)cir[j] * 64], acc);
  }
  acc += __shfl_xor(acc, 32);
  Z   += __shfl_xor(Z, 32);
  if (lane < 32)
    ao[((size_t)(b * LQ + r0 + rsel)) * 64 + h * 16 + dd] = acc / Z;
}

// ---------------------------------------------------------------------------
// FUSED cross-FFN + MGAN-pre(layer 0):
//   x1 = LN(ao@Wo + q); h = relu(x1@W1+b1); x = LN(h@W2+b2 + x1);
//   qn = LN(x); sg = sigmoid(qn@fc1+b)*( qn@fc2+b ); qp = (sg@Wq)*0.25
// x never touches HBM. Weights staged sequentially through Wl.
// grid 750, 16 rows/block. LDS ~40.7 KB -> 4 blocks/CU.
// ---------------------------------------------------------------------------
__global__ __launch_bounds__(256) void cross_ffn_pre_kernel(
    const float* __restrict__ ao, const float* __restrict__ qres,
    const float* __restrict__ Wo,
    const float* __restrict__ g1, const float* __restrict__ b1n,
    const float* __restrict__ W1, const float* __restrict__ bb1,
    const float* __restrict__ W2, const float* __restrict__ bb2,
    const float* __restrict__ g2, const float* __restrict__ b2n,
    const float* __restrict__ mlng, const float* __restrict__ mlnb,
    const float* __restrict__ fc1W, const float* __restrict__ fc1b,
    const float* __restrict__ fc2W, const float* __restrict__ fc2b,
    const float* __restrict__ Wq,
    float* __restrict__ qn_out, float* __restrict__ sg_out,
    float* __restrict__ qp_out)
{
  __shared__ float Wl[64 * 65];
  __shared__ float xs[16][64];
  __shared__ float hs[16][256];
  __shared__ float sgs[16][64];
  const int t = threadIdx.x, rr = t >> 6, cc = t & 63;
  const size_t base = (size_t)blockIdx.x * 16;

  // ---- cross out-proj + residual + LN1 ----
  for (int i = t; i < 4096; i += 256) Wl[(i >> 6) * 65 + (i & 63)] = Wo[i];
  for (int i = t; i < 1024; i += 256) xs[i >> 6][i & 63] = ao[base * 64 + i];
  __syncthreads();
  float acc[4];
  #pragma unroll
  for (int p = 0; p < 4; ++p) {
    const int row = p * 4 + rr;
    float a = 0.f;
    #pragma unroll
    for (int c = 0; c < 64; ++c) a = fmaf(xs[row][c], Wl[c * 65 + cc], a);
    acc[p] = a + qres[(base + row) * 64 + cc];
  }
  __syncthreads();
  #pragma unroll
  for (int p = 0; p < 4; ++p) {
    const int row = p * 4 + rr;
    xs[row][cc] = row_ln(acc[p], g1[cc], b1n[cc]);
  }
  __syncthreads();
  // ---- FFN1 (thread t owns hidden col t) ----
  {
    float hv[16];
    #pragma unroll
    for (int r = 0; r < 16; ++r) hv[r] = 0.f;
    #pragma unroll 8
    for (int c = 0; c < 64; ++c) {
      const float w = W1[c * 256 + t];
      #pragma unroll
      for (int r = 0; r < 16; ++r) hv[r] = fmaf(xs[r][c], w, hv[r]);
    }
    const float bb = bb1[t];
    #pragma unroll
    for (int r = 0; r < 16; ++r) hs[r][t] = fmaxf(hv[r] + bb, 0.f);
  }
  // ---- FFN2 via 4 LDS-staged 64x64 chunks of W2 ----
  float acc2[4];
  #pragma unroll
  for (int p = 0; p < 4; ++p) acc2[p] = bb2[cc];
  for (int ch = 0; ch < 4; ++ch) {
    __syncthreads();
    for (int i = t; i < 4096; i += 256)
      Wl[(i >> 6) * 65 + (i & 63)] = W2[(ch * 64 + (i >> 6)) * 64 + (i & 63)];
    __syncthreads();
    #pragma unroll
    for (int p = 0; p < 4; ++p) {
      const int row = p * 4 + rr;
      #pragma unroll
      for (int c = 0; c < 64; ++c)
        acc2[p] = fmaf(hs[row][ch * 64 + c], Wl[c * 65 + cc], acc2[p]);
    }
  }
  // ---- LN2 -> x; then qn = LN(x) (x stays on-chip) ----
  __syncthreads();
  #pragma unroll
  for (int p = 0; p < 4; ++p) {
    const int row = p * 4 + rr;
    const size_t idx = (base + row) * 64 + cc;
    const float xv = row_ln(acc2[p] + xs[row][cc], g2[cc], b2n[cc]);
    const float qv = row_ln(xv, mlng[cc], mlnb[cc]);
    qn_out[idx] = qv;
    hs[row][cc] = qv;     // reuse hs[...][0..63] as qn tile
  }
  __syncthreads();
  // ---- sg = sigmoid(qn@fc1+b1)*(qn@fc2+b2) ----
  for (int i = t; i < 4096; i += 256) Wl[(i >> 6) * 65 + (i & 63)] = fc1W[i];
  __syncthreads();
  float d1[4];
  #pragma unroll
  for (int p = 0; p < 4; ++p) {
    const int row = p * 4 + rr;
    float a = fc1b[cc];
    #pragma unroll
    for (int c = 0; c < 64; ++c) a = fmaf(hs[row][c], Wl[c * 65 + cc], a);
    d1[p] = a;
  }
  __syncthreads();
  for (int i = t; i < 4096; i += 256) Wl[(i >> 6) * 65 + (i & 63)] = fc2W[i];
  __syncthreads();
  #pragma unroll
  for (int p = 0; p < 4; ++p) {
    const int row = p * 4 + rr;
    const size_t idx = (base + row) * 64 + cc;
    float a = fc2b[cc];
    #pragma unroll
    for (int c = 0; c < 64; ++c) a = fmaf(hs[row][c], Wl[c * 65 + cc], a);
    const float sv = sigmoidf(d1[p]) * a;
    sg_out[idx] = sv;
    sgs[row][cc] = sv;
  }
  __syncthreads();
  // ---- qp = (sg@Wq)*0.25 ----
  for (int i = t; i < 4096; i += 256) Wl[(i >> 6) * 65 + (i & 63)] = Wq[i];
  __syncthreads();
  #pragma unroll
  for (int p = 0; p < 4; ++p) {
    const int row = p * 4 + rr;
    float a = 0.f;
    #pragma unroll
    for (int c = 0; c < 64; ++c) a = fmaf(sgs[row][c], Wl[c * 65 + cc], a);
    qp_out[(base + row) * 64 + cc] = a * 0.25f;
  }
}

// ---------------------------------------------------------------------------
// Fused awg_out(layer i) + mgan_pre(layer i+1): x never touches HBM.
// grid 750, 16 rows/block.
// ---------------------------------------------------------------------------
__global__ __launch_bounds__(256) void out_pre_kernel(
    const float* __restrict__ ao, const float* __restrict__ sg,
    const float* __restrict__ qn, const float* __restrict__ Wo,
    const float* __restrict__ g_, const float* __restrict__ b_,
    const float* __restrict__ lng, const float* __restrict__ lnb,
    const float* __restrict__ W1, const float* __restrict__ bb1,
    const float* __restrict__ W2, const float* __restrict__ bb2,
    const float* __restrict__ Wq,
    float* __restrict__ qn_out, float* __restrict__ sg_out,
    float* __restrict__ qp_out)
{
  __shared__ float Wl[64 * 65];
  __shared__ float xs[16][64];
  __shared__ float sgs[16][64];
  const int t = threadIdx.x, rr = t >> 6, cc = t & 63;
  const size_t base = (size_t)blockIdx.x * 16;
  for (int i = t; i < 4096; i += 256) Wl[(i >> 6) * 65 + (i & 63)] = Wo[i];
  for (int i = t; i < 1024; i += 256) xs[i >> 6][i & 63] = ao[base * 64 + i];
  __syncthreads();
  float accp[4], sgv[4];
  #pragma unroll
  for (int p = 0; p < 4; ++p) {
    const int row = p * 4 + rr;
    const size_t idx = (base + row) * 64 + cc;
    float a = 0.f;
    #pragma unroll
    for (int c = 0; c < 64; ++c) a = fmaf(xs[row][c], Wl[c * 65 + cc], a);
    sgv[p] = sg[idx];
    accp[p] = a + sgv[p];
  }
  __syncthreads();
  #pragma unroll
  for (int p = 0; p < 4; ++p) {
    const int row = p * 4 + rr;
    const size_t idx = (base + row) * 64 + cc;
    const float awg = row_ln(accp[p], g_[cc], b_[cc]);
    const float xv = qn[idx] + sgv[p] * sigmoidf(awg);
    const float qv = row_ln(xv, lng[cc], lnb[cc]);
    qn_out[idx] = qv;
    xs[row][cc] = qv;
  }
  __syncthreads();
  for (int i = t; i < 4096; i += 256) Wl[(i >> 6) * 65 + (i & 63)] = W1[i];
  __syncthreads();
  float d1[4];
  #pragma unroll
  for (int p = 0; p < 4; ++p) {
    const int row = p * 4 + rr;
    float a = bb1[cc];
    #pragma unroll
    for (int c = 0; c < 64; ++c) a = fmaf(xs[row][c], Wl[c * 65 + cc], a);
    d1[p] = a;
  }
  __syncthreads();
  for (int i = t; i < 4096; i += 256) Wl[(i >> 6) * 65 + (i & 63)] = W2[i];
  __syncthreads();
  #pragma unroll
  for (int p = 0; p < 4; ++p) {
    const int row = p * 4 + rr;
    const size_t idx = (base + row) * 64 + cc;
    float a = bb2[cc];
    #pragma unroll
    for (int c = 0; c < 64; ++c) a = fmaf(xs[row][c], Wl[c * 65 + cc], a);
    const float sv = sigmoidf(d1[p]) * a;
    sg_out[idx] = sv;
    sgs[row][cc] = sv;
  }
  __syncthreads();
  for (int i = t; i < 4096; i += 256) Wl[(i >> 6) * 65 + (i & 63)] = Wq[i];
  __syncthreads();
  #pragma unroll
  for (int p = 0; p < 4; ++p) {
    const int row = p * 4 + rr;
    float a = 0.f;
    #pragma unroll
    for (int c = 0; c < 64; ++c) a = fmaf(sgs[row][c], Wl[c * 65 + cc], a);
    qp_out[(base + row) * 64 + cc] = a * 0.25f;
  }
}

// ---------------------------------------------------------------------------
// Fused awg_out(layer 1) + head: out = sigmoid(x2 @ fcW + fcb).
// grid 750, 16 rows/block. Output fp32.
// ---------------------------------------------------------------------------
__global__ __launch_bounds__(256) void out_final_kernel(
    const float* __restrict__ ao, const float* __restrict__ sg,
    const float* __restrict__ qn, const float* __restrict__ Wo,
    const float* __restrict__ g_, const float* __restrict__ b_,
    const float* __restrict__ fw, const float* __restrict__ fb,
    float* __restrict__ out)
{
  __shared__ float Wl[64 * 65];
  __shared__ float xs[16][64];
  const int t = threadIdx.x, rr = t >> 6, cc = t & 63;
  const size_t base = (size_t)blockIdx.x * 16;
  for (int i = t; i < 4096; i += 256) Wl[(i >> 6) * 65 + (i & 63)] = Wo[i];
  for (int i = t; i < 1024; i += 256) xs[i >> 6][i & 63] = ao[base * 64 + i];
  __syncthreads();
  #pragma unroll
  for (int p = 0; p < 4; ++p) {
    const int row = p * 4 + rr;
    const size_t idx = (base + row) * 64 + cc;
    float a = 0.f;
    #pragma unroll
    for (int c = 0; c < 64; ++c) a = fmaf(xs[row][c], Wl[c * 65 + cc], a);
    const float sgv = sg[idx];
    a += sgv;
    const float awg = row_ln(a, g_[cc], b_[cc]);
    const float xv = qn[idx] + sgv * sigmoidf(awg);
    float v = xv * fw[cc];
    #pragma unroll
    for (int off = 32; off > 0; off >>= 1) v += __shfl_xor(v, off);
    if (cc == 0) out[base + row] = sigmoidf(v + fb[0]);
  }
}

// ---------------------------------------------------------------------------
extern "C" void kernel_launch(void* const* d_in, const int* in_sizes, int n_in,
                              void* d_out, int out_size, void* d_ws, size_t ws_size,
                              hipStream_t stream) {
  (void)in_sizes; (void)n_in; (void)out_size; (void)ws_size;

  const float* q     = (const float*)d_in[0];
  const float* enc   = (const float*)d_in[1];
  const float* calWq = (const float*)d_in[2];
  const float* calWk = (const float*)d_in[3];
  const float* calWv = (const float*)d_in[4];
  const float* calWo = (const float*)d_in[5];
  const float* ln1g  = (const float*)d_in[6];
  const float* ln1b  = (const float*)d_in[7];
  const float* W1    = (const float*)d_in[8];
  const float* b1v   = (const float*)d_in[9];
  const float* W2    = (const float*)d_in[10];
  const float* b2v   = (const float*)d_in[11];
  const float* ln2g  = (const float*)d_in[12];
  const float* ln2b  = (const float*)d_in[13];
  const float* mlng  = (const float*)d_in[14];
  const float* mlnb  = (const float*)d_in[15];
  const float* mfc1W = (const float*)d_in[16];
  const float* mfc1b = (const float*)d_in[17];
  const float* mfc2W = (const float*)d_in[18];
  const float* mfc2b = (const float*)d_in[19];
  const float* mWq   = (const float*)d_in[20];
  const float* mWk   = (const float*)d_in[21];
  const float* mWv   = (const float*)d_in[22];
  const float* mWo   = (const float*)d_in[23];
  const float* malng = (const float*)d_in[24];
  const float* malnb = (const float*)d_in[25];
  const float* fcW   = (const float*)d_in[26];
  const float* fcb   = (const float*)d_in[27];
  float* out = (float*)d_out;

  float* ws  = (float*)d_ws;
  float* kv  = ws + WS_KV;
  float* qp  = ws + WS_QP;
  float* aob = ws + WS_AO;
  float* qnb = ws + WS_QN;
  float* sgb = ws + WS_SG;

  const size_t crossLds = 2 * 4 * PITCH * 8 + 4 * 1024;            // 52,288 B
  const size_t awgLds   = 4 * PITCH * 8 + 1024 + 768 + 384;        // 26,272 B

  // 1) all K/V projections + cross q-projection in one dispatch
  kvq_proj_kernel<<<dim3(750, 7), 256, 0, stream>>>(enc, q, calWq, calWk, calWv,
                                                    mWk, mWv, kv, qp);

  // 2) cross attention + fused FFN/LN + MGAN-pre(0) epilogue
  cross_attn_kernel<<<dim3(375, NH_, B_), 256, crossLds, stream>>>(qp, kv, kv + 192000, aob);
  cross_ffn_pre_kernel<<<750, 256, 0, stream>>>(aob, q, calWo, ln1g, ln1b,
                                                W1, b1v, W2, b2v, ln2g, ln2b,
                                                mlng, mlnb, mfc1W, mfc1b,
                                                mfc2W, mfc2b, mWq,
                                                qnb, sgb, qp);

  // 3) MGAN layer 0 attention + fused awg_out(0)+mgan_pre(1)
  awg_attn_kernel<<<dim3(375, NH_, B_), 256, awgLds, stream>>>(
      qp, kv + 2 * 192000, kv + 3 * 192000, aob);
  out_pre_kernel<<<750, 256, 0, stream>>>(aob, sgb, qnb, mWo, malng, malnb,
                                          mlng + 64, mlnb + 64,
                                          mfc1W + 4096, mfc1b + 64,
                                          mfc2W + 4096, mfc2b + 64,
                                          mWq + 4096, qnb, sgb, qp);

  // 4) MGAN layer 1 + head
  awg_attn_kernel<<<dim3(375, NH_, B_), 256, awgLds, stream>>>(
      qp, kv + 4 * 192000, kv + 5 * 192000, aob);
  out_final_kernel<<<750, 256, 0, stream>>>(aob, sgb, qnb, mWo + 4096,
                                            malng + 64, malnb + 64, fcW, fcb, out);
}

// Round 13
// 446.925 us; speedup vs baseline: 1.0788x; 1.0788x over previous
//
#include <hip/hip_runtime.h>
#include <hip/hip_bf16.h>

using bf16 = __hip_bfloat16;

#define DEV_INLINE __device__ __forceinline__

// Problem constants
constexpr int B_  = 4;
constexpr int LQ  = 3000;
constexpr int LK  = 750;
constexpr int NH_ = 4;
constexpr float EPSF = 1e-6f;

// LDS pitch in uint2 elements per d4-row (>=750, odd)
constexpr int PITCH = 753;

// Workspace layout (fp32 elements).
constexpr size_t WS_KV = 0;        // 6 x B*LK*64 = 1,152,000
constexpr size_t WS_XB = 1152000;  // B*LQ*64 = 768,000
constexpr size_t WS_QP = 1920000;  // 768,000
constexpr size_t WS_AO = 2688000;  // 768,000
constexpr size_t WS_QN = 3456000;  // 768,000
constexpr size_t WS_SG = 4224000;  // 768,000

typedef _Float16 half2_t __attribute__((ext_vector_type(2)));

DEV_INLINE float sigmoidf(float x) { return 1.f / (1.f + __expf(-x)); }

DEV_INLINE unsigned int packh2(float a, float b) {
  half2_t h = { (_Float16)a, (_Float16)b };
  unsigned int u; __builtin_memcpy(&u, &h, 4); return u;
}
DEV_INLINE half2_t u2h(unsigned int u) {
  half2_t h; __builtin_memcpy(&h, &u, 4); return h;
}
// one v_dot2_f32_f16: acc + k.x*q.x + k.y*q.y
DEV_INLINE float dot2(unsigned int kw, half2_t qh, float acc) {
  return __builtin_amdgcn_fdot2(u2h(kw), qh, acc, false);
}

DEV_INLINE unsigned int f2sort(float f) {
  int ib = __float_as_int(f);
  return (unsigned int)(ib ^ ((ib >> 31) | 0x80000000));
}

DEV_INLINE unsigned int bcastu(unsigned int v) {
  return (unsigned int)__builtin_amdgcn_readfirstlane((int)v);
}

DEV_INLINE float row_ln(float v, float g, float b) {
  float s1 = v, s2 = v * v;
  #pragma unroll
  for (int off = 32; off > 0; off >>= 1) {
    s1 += __shfl_xor(s1, off);
    s2 += __shfl_xor(s2, off);
  }
  const float m   = s1 * (1.f / 64.f);
  const float var = s2 * (1.f / 64.f) - m * m;
  return (v - m) * rsqrtf(var + EPSF) * g + b;
}

// ---------------------------------------------------------------------------
// Merged projections: y<6 -> K/V of enc (188 blocks used); y==6 -> q-proj
// (750 blocks). 16 rows/block.
// ---------------------------------------------------------------------------
__global__ __launch_bounds__(256) void kvq_proj_kernel(
    const float* __restrict__ enc, const float* __restrict__ q,
    const float* __restrict__ calWq,
    const float* __restrict__ calWk, const float* __restrict__ calWv,
    const float* __restrict__ mWk, const float* __restrict__ mWv,
    float* __restrict__ kv, float* __restrict__ qp)
{
  const int y = blockIdx.y;
  if (y < 6 && blockIdx.x >= 188) return;
  __shared__ float Wl[64 * 65];
  __shared__ float xs[16][64];
  const int t = threadIdx.x, rr = t >> 6, cc = t & 63;
  const float* W;
  const float* src;
  float* dst;
  float scale = 1.f;
  int nrows = 3000;
  switch (y) {
    case 0: W = calWk; src = enc; dst = kv;               break;
    case 1: W = calWv; src = enc; dst = kv + 192000;      break;
    case 2: W = mWk;        src = enc; dst = kv + 384000; break;
    case 3: W = mWv;        src = enc; dst = kv + 576000; break;
    case 4: W = mWk + 4096; src = enc; dst = kv + 768000; break;
    case 5: W = mWv + 4096; src = enc; dst = kv + 960000; break;
    default: W = calWq; src = q; dst = qp; scale = 0.25f; nrows = 12000; break;
  }
  for (int i = t; i < 4096; i += 256) Wl[(i >> 6) * 65 + (i & 63)] = W[i];
  const int base = blockIdx.x * 16;
  for (int i = t; i < 1024; i += 256) {
    const int grow = base + (i >> 6);
    xs[i >> 6][i & 63] = (grow < nrows) ? src[(size_t)grow * 64 + (i & 63)] : 0.f;
  }
  __syncthreads();
  #pragma unroll
  for (int p = 0; p < 4; ++p) {
    const int row = p * 4 + rr;
    const int grow = base + row;
    float acc = 0.f;
    #pragma unroll
    for (int c = 0; c < 64; ++c) acc = fmaf(xs[row][c], Wl[c * 65 + cc], acc);
    if (grow < nrows) dst[(size_t)grow * 64 + cc] = acc * scale;
  }
}

// ---------------------------------------------------------------------------
// CROSS attention (round-10 verified: 94.5 us). grid (375, NH, B), block 256.
// K,V both staged upfront as packed-f16 uint2; QK^T via v_dot2_f32_f16;
// PV via fma_mix; barrier-free per-wave swizzled PV reduce.
// LDS 52,288 B -> 3 blocks/CU. NOTE (r11): phased K->V LDS reuse REGRESSED.
// ---------------------------------------------------------------------------
__global__ __launch_bounds__(256) void cross_attn_kernel(
    const float* __restrict__ qp, const float* __restrict__ kp,
    const float* __restrict__ vp, float* __restrict__ ao)
{
  extern __shared__ char smem[];
  uint2* KT2 = (uint2*)smem;                        // [4][PITCH]
  uint2* VT2 = KT2 + 4 * PITCH;                     // [4][PITCH]
  float* red = (float*)(smem + 2 * 4 * PITCH * 8);  // [4 waves][256]

  const int t = threadIdx.x;
  const int h = blockIdx.y, b = blockIdx.z;
  const float* kslab = kp + (size_t)(b * LK) * 64 + h * 16;
  const float* vslab = vp + (size_t)(b * LK) * 64 + h * 16;

  for (int k = t; k < LK; k += 256) {
    const float4* ks = (const float4*)(kslab + (size_t)k * 64);
    const float4* vs = (const float4*)(vslab + (size_t)k * 64);
    #pragma unroll
    for (int q4 = 0; q4 < 4; ++q4) {
      float4 a = ks[q4], v = vs[q4];
      KT2[q4 * PITCH + k] = make_uint2(packh2(a.x, a.y), packh2(a.z, a.w));
      VT2[q4 * PITCH + k] = make_uint2(packh2(v.x, v.y), packh2(v.z, v.w));
    }
  }
  __syncthreads();

  const int wave = t >> 6, lane = t & 63;
  const int r0 = blockIdx.x * 8 + wave * 2;
  const float* qrow = qp + ((size_t)(b * LQ + r0)) * 64 + h * 16;
  half2_t qh0[8], qh1[8];
  #pragma unroll
  for (int i = 0; i < 8; ++i) {
    qh0[i] = u2h(packh2(qrow[2 * i], qrow[2 * i + 1]));
    qh1[i] = u2h(packh2(qrow[64 + 2 * i], qrow[64 + 2 * i + 1]));
  }

  float lg0[12], lg1[12];
  #pragma unroll
  for (int tt = 0; tt < 12; ++tt) {
    const int k = lane + (tt << 6);
    if (tt < 11 || k < LK) {
      float a0 = 0.f, a1 = 0.f;
      #pragma unroll
      for (int d4 = 0; d4 < 4; ++d4) {
        const uint2 w = KT2[d4 * PITCH + k];
        a0 = dot2(w.x, qh0[2 * d4], a0); a0 = dot2(w.y, qh0[2 * d4 + 1], a0);
        a1 = dot2(w.x, qh1[2 * d4], a1); a1 = dot2(w.y, qh1[2 * d4 + 1], a1);
      }
      lg0[tt] = a0; lg1[tt] = a1;
    } else {
      lg0[tt] = -1e30f; lg1[tt] = -1e30f;
    }
  }

  float m0 = lg0[0], m1 = lg1[0];
  #pragma unroll
  for (int tt = 1; tt < 12; ++tt) { m0 = fmaxf(m0, lg0[tt]); m1 = fmaxf(m1, lg1[tt]); }
  #pragma unroll
  for (int off = 32; off > 0; off >>= 1) {
    m0 = fmaxf(m0, __shfl_xor(m0, off));
    m1 = fmaxf(m1, __shfl_xor(m1, off));
  }
  float s0 = 0.f, s1 = 0.f;
  #pragma unroll
  for (int tt = 0; tt < 12; ++tt) {
    lg0[tt] = __expf(lg0[tt] - m0); s0 += lg0[tt];
    lg1[tt] = __expf(lg1[tt] - m1); s1 += lg1[tt];
  }
  #pragma unroll
  for (int off = 32; off > 0; off >>= 1) {
    s0 += __shfl_xor(s0, off);
    s1 += __shfl_xor(s1, off);
  }
  const float inv0 = 1.f / s0, inv1 = 1.f / s1;

  float* red_w = red + wave * 256;
  const int dd = lane & 3, g = lane >> 2;
  float* aor0 = ao + ((size_t)(b * LQ + r0)) * 64 + h * 16;
  float* aor1 = aor0 + 64;

  #pragma unroll
  for (int c = 0; c < 4; ++c) {
    float o0[4] = {0.f, 0.f, 0.f, 0.f}, o1[4] = {0.f, 0.f, 0.f, 0.f};
    #pragma unroll
    for (int tt = 0; tt < 12; ++tt) {
      const int k = lane + (tt << 6);
      if (tt < 11 || k < LK) {
        const float w0 = lg0[tt], w1 = lg1[tt];
        const uint2 w = VT2[c * PITCH + k];
        const half2_t va = u2h(w.x), vb = u2h(w.y);
        // (float)h folds into v_fma_mix_f32
        o0[0] = fmaf(w0, (float)va.x, o0[0]); o0[1] = fmaf(w0, (float)va.y, o0[1]);
        o0[2] = fmaf(w0, (float)vb.x, o0[2]); o0[3] = fmaf(w0, (float)vb.y, o0[3]);
        o1[0] = fmaf(w1, (float)va.x, o1[0]); o1[1] = fmaf(w1, (float)va.y, o1[1]);
        o1[2] = fmaf(w1, (float)vb.x, o1[2]); o1[3] = fmaf(w1, (float)vb.y, o1[3]);
      }
    }
    #pragma unroll
    for (int d = 0; d < 4; ++d) red_w[d * 64 + ((lane + 16 * d) & 63)] = o0[d];
    float a = 0.f;
    #pragma unroll
    for (int j = 0; j < 4; ++j)
      a += red_w[dd * 64 + ((g + 16 * j + 16 * dd) & 63)];
    #pragma unroll
    for (int off = 4; off <= 32; off <<= 1) a += __shfl_xor(a, off);
    if (g == 0) aor0[c * 4 + dd] = a * inv0;
    #pragma unroll
    for (int d = 0; d < 4; ++d) red_w[d * 64 + ((lane + 16 * d) & 63)] = o1[d];
    float a1r = 0.f;
    #pragma unroll
    for (int j = 0; j < 4; ++j)
      a1r += red_w[dd * 64 + ((g + 16 * j + 16 * dd) & 63)];
    #pragma unroll
    for (int off = 4; off <= 32; off <<= 1) a1r += __shfl_xor(a1r, off);
    if (g == 1) aor1[c * 4 + dd] = a1r * inv1;
  }
}

// ---------------------------------------------------------------------------
// AWG attention. grid (375, NH, B), block 256. K packed-f16 uint2 in LDS;
// logits via v_dot2_f32_f16 (recompute path bit-identical). Exact-on-f16K
// top-16 via 3-stage ballot select; V gathered from L2.
// LDS: 24,096 + 1,024 + 768 + 384 = 26,272 B -> 6 blocks/CU.
// ---------------------------------------------------------------------------
__global__ __launch_bounds__(256) void awg_attn_kernel(
    const float* __restrict__ qp, const float* __restrict__ kp,
    const float* __restrict__ vp, float* __restrict__ ao)
{
  extern __shared__ char smem[];
  uint2*          KT2   = (uint2*)smem;                              // [4][PITCH]
  unsigned short* candi = (unsigned short*)(smem + 4 * PITCH * 8);   // [4][2][64]
  float*          cw    = (float*)(smem + 4 * PITCH * 8 + 1024);     // [4][2][24]
  unsigned short* ciw   = (unsigned short*)(smem + 4 * PITCH * 8 + 1024 + 768);

  const int t = threadIdx.x;
  const int h = blockIdx.y, b = blockIdx.z;
  const float* kslab = kp + (size_t)(b * LK) * 64 + h * 16;

  for (int k = t; k < LK; k += 256) {
    const float4* ks = (const float4*)(kslab + (size_t)k * 64);
    #pragma unroll
    for (int q4 = 0; q4 < 4; ++q4) {
      float4 a = ks[q4];
      KT2[q4 * PITCH + k] = make_uint2(packh2(a.x, a.y), packh2(a.z, a.w));
    }
  }
  __syncthreads();

  const int wave = t >> 6, lane = t & 63;
  const unsigned long long below = (1ull << lane) - 1ull;
  unsigned short* ci0 = candi + wave * 128;
  unsigned short* ci1 = ci0 + 64;
  float* cw0 = cw + wave * 48;      float* cw1 = cw0 + 24;
  unsigned short* cio0 = ciw + wave * 48; unsigned short* cio1 = cio0 + 24;

  const int r0 = blockIdx.x * 8 + wave * 2;
  const float* qrow = qp + ((size_t)(b * LQ + r0)) * 64 + h * 16;
  unsigned int qw0[8], qw1[8];   // wave-uniform packed f16 q -> SGPRs
  #pragma unroll
  for (int i = 0; i < 8; ++i) {
    qw0[i] = bcastu(packh2(qrow[2 * i], qrow[2 * i + 1]));
    qw1[i] = bcastu(packh2(qrow[64 + 2 * i], qrow[64 + 2 * i + 1]));
  }

  float lg0[12], lg1[12];
  #pragma unroll
  for (int tt = 0; tt < 12; ++tt) {
    const int k = lane + (tt << 6);
    if (tt < 11 || k < LK) {
      float a0 = 0.f, a1 = 0.f;
      #pragma unroll
      for (int d4 = 0; d4 < 4; ++d4) {
        const uint2 w = KT2[d4 * PITCH + k];
        a0 = dot2(w.x, u2h(qw0[2 * d4]), a0); a0 = dot2(w.y, u2h(qw0[2 * d4 + 1]), a0);
        a1 = dot2(w.x, u2h(qw1[2 * d4]), a1); a1 = dot2(w.y, u2h(qw1[2 * d4 + 1]), a1);
      }
      lg0[tt] = a0; lg1[tt] = a1;
    } else {
      lg0[tt] = -3.0e38f; lg1[tt] = -3.0e38f;
    }
  }

  float fm0 = lg0[0], fm1 = lg1[0];
  #pragma unroll
  for (int tt = 1; tt < 12; ++tt) { fm0 = fmaxf(fm0, lg0[tt]); fm1 = fmaxf(fm1, lg1[tt]); }
  float M0 = fm0, M1 = fm1;
  #pragma unroll
  for (int off = 32; off > 0; off >>= 1) {
    M0 = fmaxf(M0, __shfl_xor(M0, off));
    M1 = fmaxf(M1, __shfl_xor(M1, off));
  }
  const unsigned int head0 = f2sort(fm0), head1 = f2sort(fm1);

  unsigned int L0 = 0u, L1 = 0u;
  #pragma unroll
  for (int bit = 31; bit >= 20; --bit) {
    const unsigned int c0 = L0 | (1u << bit);
    const unsigned int c1 = L1 | (1u << bit);
    if (__popcll(__ballot(head0 >= c0)) >= 16) L0 = c0;
    if (__popcll(__ballot(head1 >= c1)) >= 16) L1 = c1;
  }

  int base0 = 0, base1 = 0;
  #pragma unroll
  for (int tt = 0; tt < 12; ++tt) {
    const int k = lane + (tt << 6);
    const bool p0 = f2sort(lg0[tt]) >= L0;
    const bool p1 = f2sort(lg1[tt]) >= L1;
    const unsigned long long m0 = __ballot(p0);
    const unsigned long long m1 = __ballot(p1);
    if (p0) {
      const int pos = base0 + __popcll(m0 & below);
      if (pos < 64) ci0[pos] = (unsigned short)k;
    }
    if (p1) {
      const int pos = base1 + __popcll(m1 & below);
      if (pos < 64) ci1[pos] = (unsigned short)k;
    }
    base0 += __popcll(m0);
    base1 += __popcll(m1);
  }
  const int C0 = min(base0, 64), C1 = min(base1, 64);

  // recompute candidate logits (bit-identical dot2 order)
  const int k0 = (lane < C0) ? (int)ci0[lane] : 0;
  const int k1 = (lane < C1) ? (int)ci1[lane] : 0;
  float cv0 = 0.f, cv1 = 0.f;
  #pragma unroll
  for (int d4 = 0; d4 < 4; ++d4) {
    const uint2 wa = KT2[d4 * PITCH + k0];
    const uint2 wb = KT2[d4 * PITCH + k1];
    cv0 = dot2(wa.x, u2h(qw0[2 * d4]), cv0); cv0 = dot2(wa.y, u2h(qw0[2 * d4 + 1]), cv0);
    cv1 = dot2(wb.x, u2h(qw1[2 * d4]), cv1); cv1 = dot2(wb.y, u2h(qw1[2 * d4 + 1]), cv1);
  }
  const unsigned int cu0 = (lane < C0) ? f2sort(cv0) : 0u;
  const unsigned int cu1 = (lane < C1) ? f2sort(cv1) : 0u;

  unsigned int T0 = 0u, T1 = 0u;
  #pragma unroll
  for (int bit = 31; bit >= 0; --bit) {
    const unsigned int c0 = T0 | (1u << bit);
    const unsigned int c1 = T1 | (1u << bit);
    if (__popcll(__ballot(cu0 >= c0)) >= 16) T0 = c0;
    if (__popcll(__ballot(cu1 >= c1)) >= 16) T1 = c1;
  }

  const bool w0 = (lane < C0) && (cu0 >= T0);
  const bool w1 = (lane < C1) && (cu1 >= T1);
  const unsigned long long mw0 = __ballot(w0);
  const unsigned long long mw1 = __ballot(w1);
  const int cnt0 = min((int)__popcll(mw0), 24);
  const int cnt1 = min((int)__popcll(mw1), 24);
  if (w0) {
    const int pos = __popcll(mw0 & below);
    if (pos < 24) { cw0[pos] = cv0; cio0[pos] = (unsigned short)k0; }
  }
  if (w1) {
    const int pos = __popcll(mw1 & below);
    if (pos < 24) { cw1[pos] = cv1; cio1[pos] = (unsigned short)k1; }
  }

  const int dd = lane & 15;
  const int rsel = (lane >> 4) & 1;
  const int half = lane >> 5;
  const int cnt = rsel ? cnt1 : cnt0;
  const float* cwr = rsel ? cw1 : cw0;
  const unsigned short* cir = rsel ? cio1 : cio0;
  const float ref = rsel ? M1 : M0;
  const float* vbase = vp + (size_t)(b * LK) * 64 + h * 16 + dd;
  float acc = 0.f, Z = 0.f;
  for (int j = half; j < cnt; j += 2) {
    const float e = __expf(cwr[j] - ref);
    Z += e;
    acc = fmaf(e, vbase[(size_t)cir[j] * 64], acc);
  }
  acc += __shfl_xor(acc, 32);
  Z   += __shfl_xor(Z, 32);
  if (lane < 32)
    ao[((size_t)(b * LQ + r0 + rsel)) * 64 + h * 16 + dd] = acc / Z;
}

// ---------------------------------------------------------------------------
// Fused: x1 = LN(ao@Wo + q); h = relu(x1@W1+b1); x = LN(h@W2+b2 + x1)
// W2 staged in LDS 64x64 chunks. grid 750, 16 rows/block. (r10 verified)
// ---------------------------------------------------------------------------
__global__ __launch_bounds__(256) void cross_ffn_kernel(
    const float* __restrict__ ao, const float* __restrict__ qres,
    const float* __restrict__ Wo,
    const float* __restrict__ g1, const float* __restrict__ b1n,
    const float* __restrict__ W1, const float* __restrict__ bb1,
    const float* __restrict__ W2, const float* __restrict__ bb2,
    const float* __restrict__ g2, const float* __restrict__ b2n,
    float* __restrict__ xout)
{
  __shared__ float Wl[64 * 65];
  __shared__ float xs[16][64];
  __shared__ float hs[16][256];
  const int t = threadIdx.x, rr = t >> 6, cc = t & 63;
  const size_t base = (size_t)blockIdx.x * 16;
  for (int i = t; i < 4096; i += 256) Wl[(i >> 6) * 65 + (i & 63)] = Wo[i];
  for (int i = t; i < 1024; i += 256) xs[i >> 6][i & 63] = ao[base * 64 + i];
  __syncthreads();
  float acc[4];
  #pragma unroll
  for (int p = 0; p < 4; ++p) {
    const int row = p * 4 + rr;
    float a = 0.f;
    #pragma unroll
    for (int c = 0; c < 64; ++c) a = fmaf(xs[row][c], Wl[c * 65 + cc], a);
    acc[p] = a + qres[(base + row) * 64 + cc];
  }
  __syncthreads();
  #pragma unroll
  for (int p = 0; p < 4; ++p) {
    const int row = p * 4 + rr;
    xs[row][cc] = row_ln(acc[p], g1[cc], b1n[cc]);
  }
  __syncthreads();
  {
    float hv[16];
    #pragma unroll
    for (int r = 0; r < 16; ++r) hv[r] = 0.f;
    #pragma unroll 8
    for (int c = 0; c < 64; ++c) {
      const float w = W1[c * 256 + t];
      #pragma unroll
      for (int r = 0; r < 16; ++r) hv[r] = fmaf(xs[r][c], w, hv[r]);
    }
    const float bb = bb1[t];
    #pragma unroll
    for (int r = 0; r < 16; ++r) hs[r][t] = fmaxf(hv[r] + bb, 0.f);
  }
  float acc2[4];
  #pragma unroll
  for (int p = 0; p < 4; ++p) acc2[p] = bb2[cc];
  for (int ch = 0; ch < 4; ++ch) {
    __syncthreads();
    for (int i = t; i < 4096; i += 256)
      Wl[(i >> 6) * 65 + (i & 63)] = W2[(ch * 64 + (i >> 6)) * 64 + (i & 63)];
    __syncthreads();
    #pragma unroll
    for (int p = 0; p < 4; ++p) {
      const int row = p * 4 + rr;
      #pragma unroll
      for (int c = 0; c < 64; ++c)
        acc2[p] = fmaf(hs[row][ch * 64 + c], Wl[c * 65 + cc], acc2[p]);
    }
  }
  #pragma unroll
  for (int p = 0; p < 4; ++p) {
    const int row = p * 4 + rr;
    const float a = acc2[p] + xs[row][cc];
    xout[(base + row) * 64 + cc] = row_ln(a, g2[cc], b2n[cc]);
  }
}

// ---------------------------------------------------------------------------
// MGAN pre (layer 0): qn = LN(x); sg = sigmoid(qn@W1+b1)*(qn@W2+b2);
// qp = (sg@Wq)*0.25. W1/W2 read DIRECT from global (coalesced, L2-hot) —
// removes 2 staging phases + 4 barriers (r12 lesson: barrier chains cost).
// Only Wq staged. grid 750, 16 rows/block.
// ---------------------------------------------------------------------------
__global__ __launch_bounds__(256) void mgan_pre_kernel(
    const float* __restrict__ x, const float* __restrict__ lng,
    const float* __restrict__ lnb, const float* __restrict__ W1,
    const float* __restrict__ bb1, const float* __restrict__ W2,
    const float* __restrict__ bb2, const float* __restrict__ Wq,
    float* __restrict__ qn, float* __restrict__ sg, float* __restrict__ qp)
{
  __shared__ float Wl[64 * 65];
  __shared__ float qs[16][64];
  __shared__ float sgs[16][64];
  const int t = threadIdx.x, rr = t >> 6, cc = t & 63;
  const size_t base = (size_t)blockIdx.x * 16;
  for (int i = t; i < 4096; i += 256) Wl[(i >> 6) * 65 + (i & 63)] = Wq[i];
  #pragma unroll
  for (int p = 0; p < 4; ++p) {
    const int row = p * 4 + rr;
    const float v = x[(base + row) * 64 + cc];
    const float qv = row_ln(v, lng[cc], lnb[cc]);
    qn[(base + row) * 64 + cc] = qv;
    qs[row][cc] = qv;
  }
  __syncthreads();
  // d1/d2 with weights direct from global (one load per c, reused 4 rows)
  float d1[4], d2[4];
  #pragma unroll
  for (int p = 0; p < 4; ++p) { d1[p] = bb1[cc]; d2[p] = bb2[cc]; }
  #pragma unroll 4
  for (int c = 0; c < 64; ++c) {
    const float w1 = W1[c * 64 + cc];
    const float w2 = W2[c * 64 + cc];
    #pragma unroll
    for (int p = 0; p < 4; ++p) {
      const float xv = qs[p * 4 + rr][c];
      d1[p] = fmaf(xv, w1, d1[p]);
      d2[p] = fmaf(xv, w2, d2[p]);
    }
  }
  #pragma unroll
  for (int p = 0; p < 4; ++p) {
    const int row = p * 4 + rr;
    const float sv = sigmoidf(d1[p]) * d2[p];
    sg[(base + row) * 64 + cc] = sv;
    sgs[row][cc] = sv;
  }
  __syncthreads();
  #pragma unroll
  for (int p = 0; p < 4; ++p) {
    const int row = p * 4 + rr;
    float a = 0.f;
    #pragma unroll
    for (int c = 0; c < 64; ++c) a = fmaf(sgs[row][c], Wl[c * 65 + cc], a);
    qp[(base + row) * 64 + cc] = a * 0.25f;
  }
}

// ---------------------------------------------------------------------------
// Fused awg_out(layer i) + mgan_pre(layer i+1): x never touches HBM.
// W1/W2 direct from global (removes 2 stage phases + 4 barriers).
// grid 750, 16 rows/block.
// ---------------------------------------------------------------------------
__global__ __launch_bounds__(256) void out_pre_kernel(
    const float* __restrict__ ao, const float* __restrict__ sg,
    const float* __restrict__ qn, const float* __restrict__ Wo,
    const float* __restrict__ g_, const float* __restrict__ b_,
    const float* __restrict__ lng, const float* __restrict__ lnb,
    const float* __restrict__ W1, const float* __restrict__ bb1,
    const float* __restrict__ W2, const float* __restrict__ bb2,
    const float* __restrict__ Wq,
    float* __restrict__ qn_out, float* __restrict__ sg_out,
    float* __restrict__ qp_out)
{
  __shared__ float Wl[64 * 65];
  __shared__ float xs[16][64];
  __shared__ float sgs[16][64];
  const int t = threadIdx.x, rr = t >> 6, cc = t & 63;
  const size_t base = (size_t)blockIdx.x * 16;
  for (int i = t; i < 4096; i += 256) Wl[(i >> 6) * 65 + (i & 63)] = Wo[i];
  for (int i = t; i < 1024; i += 256) xs[i >> 6][i & 63] = ao[base * 64 + i];
  __syncthreads();
  float accp[4], sgv[4];
  #pragma unroll
  for (int p = 0; p < 4; ++p) {
    const int row = p * 4 + rr;
    const size_t idx = (base + row) * 64 + cc;
    float a = 0.f;
    #pragma unroll
    for (int c = 0; c < 64; ++c) a = fmaf(xs[row][c], Wl[c * 65 + cc], a);
    sgv[p] = sg[idx];
    accp[p] = a + sgv[p];
  }
  __syncthreads();
  #pragma unroll
  for (int p = 0; p < 4; ++p) {
    const int row = p * 4 + rr;
    const size_t idx = (base + row) * 64 + cc;
    const float awg = row_ln(accp[p], g_[cc], b_[cc]);
    const float xv = qn[idx] + sgv[p] * sigmoidf(awg);
    const float qv = row_ln(xv, lng[cc], lnb[cc]);
    qn_out[idx] = qv;
    xs[row][cc] = qv;
  }
  __syncthreads();
  // stage Wq while qn tile settles; W1/W2 direct
  for (int i = t; i < 4096; i += 256) Wl[(i >> 6) * 65 + (i & 63)] = Wq[i];
  float d1[4], d2[4];
  #pragma unroll
  for (int p = 0; p < 4; ++p) { d1[p] = bb1[cc]; d2[p] = bb2[cc]; }
  #pragma unroll 4
  for (int c = 0; c < 64; ++c) {
    const float w1 = W1[c * 64 + cc];
    const float w2 = W2[c * 64 + cc];
    #pragma unroll
    for (int p = 0; p < 4; ++p) {
      const float xv = xs[p * 4 + rr][c];
      d1[p] = fmaf(xv, w1, d1[p]);
      d2[p] = fmaf(xv, w2, d2[p]);
    }
  }
  __syncthreads();
  #pragma unroll
  for (int p = 0; p < 4; ++p) {
    const int row = p * 4 + rr;
    const size_t idx = (base + row) * 64 + cc;
    const float sv = sigmoidf(d1[p]) * d2[p];
    sg_out[idx] = sv;
    sgs[row][cc] = sv;
  }
  __syncthreads();
  #pragma unroll
  for (int p = 0; p < 4; ++p) {
    const int row = p * 4 + rr;
    float a = 0.f;
    #pragma unroll
    for (int c = 0; c < 64; ++c) a = fmaf(sgs[row][c], Wl[c * 65 + cc], a);
    qp_out[(base + row) * 64 + cc] = a * 0.25f;
  }
}

// ---------------------------------------------------------------------------
// Fused awg_out(layer 1) + head: out = sigmoid(x2 @ fcW + fcb).
// grid 750, 16 rows/block. Output fp32.
// ---------------------------------------------------------------------------
__global__ __launch_bounds__(256) void out_final_kernel(
    const float* __restrict__ ao, const float* __restrict__ sg,
    const float* __restrict__ qn, const float* __restrict__ Wo,
    const float* __restrict__ g_, const float* __restrict__ b_,
    const float* __restrict__ fw, const float* __restrict__ fb,
    float* __restrict__ out)
{
  __shared__ float Wl[64 * 65];
  __shared__ float xs[16][64];
  const int t = threadIdx.x, rr = t >> 6, cc = t & 63;
  const size_t base = (size_t)blockIdx.x * 16;
  for (int i = t; i < 4096; i += 256) Wl[(i >> 6) * 65 + (i & 63)] = Wo[i];
  for (int i = t; i < 1024; i += 256) xs[i >> 6][i & 63] = ao[base * 64 + i];
  __syncthreads();
  #pragma unroll
  for (int p = 0; p < 4; ++p) {
    const int row = p * 4 + rr;
    const size_t idx = (base + row) * 64 + cc;
    float a = 0.f;
    #pragma unroll
    for (int c = 0; c < 64; ++c) a = fmaf(xs[row][c], Wl[c * 65 + cc], a);
    const float sgv = sg[idx];
    a += sgv;
    const float awg = row_ln(a, g_[cc], b_[cc]);
    const float xv = qn[idx] + sgv * sigmoidf(awg);
    float v = xv * fw[cc];
    #pragma unroll
    for (int off = 32; off > 0; off >>= 1) v += __shfl_xor(v, off);
    if (cc == 0) out[base + row] = sigmoidf(v + fb[0]);
  }
}

// ---------------------------------------------------------------------------
extern "C" void kernel_launch(void* const* d_in, const int* in_sizes, int n_in,
                              void* d_out, int out_size, void* d_ws, size_t ws_size,
                              hipStream_t stream) {
  (void)in_sizes; (void)n_in; (void)out_size; (void)ws_size;

  const float* q     = (const float*)d_in[0];
  const float* enc   = (const float*)d_in[1];
  const float* calWq = (const float*)d_in[2];
  const float* calWk = (const float*)d_in[3];
  const float* calWv = (const float*)d_in[4];
  const float* calWo = (const float*)d_in[5];
  const float* ln1g  = (const float*)d_in[6];
  const float* ln1b  = (const float*)d_in[7];
  const float* W1    = (const float*)d_in[8];
  const float* b1v   = (const float*)d_in[9];
  const float* W2    = (const float*)d_in[10];
  const float* b2v   = (const float*)d_in[11];
  const float* ln2g  = (const float*)d_in[12];
  const float* ln2b  = (const float*)d_in[13];
  const float* mlng  = (const float*)d_in[14];
  const float* mlnb  = (const float*)d_in[15];
  const float* mfc1W = (const float*)d_in[16];
  const float* mfc1b = (const float*)d_in[17];
  const float* mfc2W = (const float*)d_in[18];
  const float* mfc2b = (const float*)d_in[19];
  const float* mWq   = (const float*)d_in[20];
  const float* mWk   = (const float*)d_in[21];
  const float* mWv   = (const float*)d_in[22];
  const float* mWo   = (const float*)d_in[23];
  const float* malng = (const float*)d_in[24];
  const float* malnb = (const float*)d_in[25];
  const float* fcW   = (const float*)d_in[26];
  const float* fcb   = (const float*)d_in[27];
  float* out = (float*)d_out;

  float* ws  = (float*)d_ws;
  float* kv  = ws + WS_KV;
  float* qp  = ws + WS_QP;
  float* aob = ws + WS_AO;
  float* qnb = ws + WS_QN;
  float* sgb = ws + WS_SG;
  float* xb  = ws + WS_XB;

  const size_t crossLds = 2 * 4 * PITCH * 8 + 4 * 1024;            // 52,288 B
  const size_t awgLds   = 4 * PITCH * 8 + 1024 + 768 + 384;        // 26,272 B

  // 1) all K/V projections + cross q-projection in one dispatch
  kvq_proj_kernel<<<dim3(750, 7), 256, 0, stream>>>(enc, q, calWq, calWk, calWv,
                                                    mWk, mWv, kv, qp);

  // 2) cross attention + fused FFN epilogue
  cross_attn_kernel<<<dim3(375, NH_, B_), 256, crossLds, stream>>>(qp, kv, kv + 192000, aob);
  cross_ffn_kernel<<<750, 256, 0, stream>>>(aob, q, calWo, ln1g, ln1b,
                                            W1, b1v, W2, b2v, ln2g, ln2b, xb);

  // 3) MGAN layer 0
  mgan_pre_kernel<<<750, 256, 0, stream>>>(xb, mlng, mlnb, mfc1W, mfc1b,
                                           mfc2W, mfc2b, mWq, qnb, sgb, qp);
  awg_attn_kernel<<<dim3(375, NH_, B_), 256, awgLds, stream>>>(
      qp, kv + 2 * 192000, kv + 3 * 192000, aob);
  out_pre_kernel<<<750, 256, 0, stream>>>(aob, sgb, qnb, mWo, malng, malnb,
                                          mlng + 64, mlnb + 64,
                                          mfc1W + 4096, mfc1b + 64,
                                          mfc2W + 4096, mfc2b + 64,
                                          mWq + 4096, qnb, sgb, qp);

  // 4) MGAN layer 1 + head
  awg_attn_kernel<<<dim3(375, NH_, B_), 256, awgLds, stream>>>(
      qp, kv + 4 * 192000, kv + 5 * 192000, aob);
  out_final_kernel<<<750, 256, 0, stream>>>(aob, sgb, qnb, mWo + 4096,
                                            malng + 64, malnb + 64, fcW, fcb, out);
}

// Round 15
// 390.176 us; speedup vs baseline: 1.2356x; 1.1454x over previous
//
#include <hip/hip_runtime.h>
#include <hip/hip_bf16.h>

using bf16 = __hip_bfloat16;

#define DEV_INLINE __device__ __forceinline__

// Problem constants
constexpr int B_  = 4;
constexpr int LQ  = 3000;
constexpr int LK  = 750;
constexpr int NH_ = 4;
constexpr float EPSF = 1e-6f;

// LDS pitch in uint2 elements per d4-row (>=750, odd) — awg kernel
constexpr int PITCH = 753;

// Workspace layout (fp32 elements).
constexpr size_t WS_KV = 0;        // 6 x B*LK*64 = 1,152,000
constexpr size_t WS_XB = 1152000;  // B*LQ*64 = 768,000
constexpr size_t WS_QP = 1920000;  // 768,000
constexpr size_t WS_AO = 2688000;  // 768,000
constexpr size_t WS_QN = 3456000;  // 768,000
constexpr size_t WS_SG = 4224000;  // 768,000

typedef _Float16 half2_t __attribute__((ext_vector_type(2)));
typedef _Float16 half4_t __attribute__((ext_vector_type(4)));
typedef float    f32x4   __attribute__((ext_vector_type(4)));

// correct gfx950 spelling (per compiler diagnostic r14): ...16x16x16f16
#define MFMA16(a, b, c) __builtin_amdgcn_mfma_f32_16x16x16f16((a), (b), (c), 0, 0, 0)

DEV_INLINE float sigmoidf(float x) { return 1.f / (1.f + __expf(-x)); }

DEV_INLINE unsigned int packh2(float a, float b) {
  half2_t h = { (_Float16)a, (_Float16)b };
  unsigned int u; __builtin_memcpy(&u, &h, 4); return u;
}
DEV_INLINE half2_t u2h(unsigned int u) {
  half2_t h; __builtin_memcpy(&h, &u, 4); return h;
}
DEV_INLINE unsigned short f2h(float f) {
  _Float16 h = (_Float16)f;
  unsigned short u; __builtin_memcpy(&u, &h, 2); return u;
}
// half4 from two 4-byte-aligned uints at p, p+2 (f16 units)
DEV_INLINE half4_t h4_from(const unsigned short* p) {
  unsigned int lo = *(const unsigned int*)p;
  unsigned int hi = *(const unsigned int*)(p + 2);
  unsigned long long v = ((unsigned long long)hi << 32) | lo;
  half4_t h; __builtin_memcpy(&h, &v, 8); return h;
}
// one v_dot2_f32_f16: acc + k.x*q.x + k.y*q.y
DEV_INLINE float dot2(unsigned int kw, half2_t qh, float acc) {
  return __builtin_amdgcn_fdot2(u2h(kw), qh, acc, false);
}

DEV_INLINE unsigned int f2sort(float f) {
  int ib = __float_as_int(f);
  return (unsigned int)(ib ^ ((ib >> 31) | 0x80000000));
}

DEV_INLINE unsigned int bcastu(unsigned int v) {
  return (unsigned int)__builtin_amdgcn_readfirstlane((int)v);
}

DEV_INLINE float row_ln(float v, float g, float b) {
  float s1 = v, s2 = v * v;
  #pragma unroll
  for (int off = 32; off > 0; off >>= 1) {
    s1 += __shfl_xor(s1, off);
    s2 += __shfl_xor(s2, off);
  }
  const float m   = s1 * (1.f / 64.f);
  const float var = s2 * (1.f / 64.f) - m * m;
  return (v - m) * rsqrtf(var + EPSF) * g + b;
}

// ---------------------------------------------------------------------------
// Merged projections: y<6 -> K/V of enc (188 blocks used); y==6 -> q-proj
// (750 blocks). 16 rows/block.
// ---------------------------------------------------------------------------
__global__ __launch_bounds__(256) void kvq_proj_kernel(
    const float* __restrict__ enc, const float* __restrict__ q,
    const float* __restrict__ calWq,
    const float* __restrict__ calWk, const float* __restrict__ calWv,
    const float* __restrict__ mWk, const float* __restrict__ mWv,
    float* __restrict__ kv, float* __restrict__ qp)
{
  const int y = blockIdx.y;
  if (y < 6 && blockIdx.x >= 188) return;
  __shared__ float Wl[64 * 65];
  __shared__ float xs[16][64];
  const int t = threadIdx.x, rr = t >> 6, cc = t & 63;
  const float* W;
  const float* src;
  float* dst;
  float scale = 1.f;
  int nrows = 3000;
  switch (y) {
    case 0: W = calWk; src = enc; dst = kv;               break;
    case 1: W = calWv; src = enc; dst = kv + 192000;      break;
    case 2: W = mWk;        src = enc; dst = kv + 384000; break;
    case 3: W = mWv;        src = enc; dst = kv + 576000; break;
    case 4: W = mWk + 4096; src = enc; dst = kv + 768000; break;
    case 5: W = mWv + 4096; src = enc; dst = kv + 960000; break;
    default: W = calWq; src = q; dst = qp; scale = 0.25f; nrows = 12000; break;
  }
  for (int i = t; i < 4096; i += 256) Wl[(i >> 6) * 65 + (i & 63)] = W[i];
  const int base = blockIdx.x * 16;
  for (int i = t; i < 1024; i += 256) {
    const int grow = base + (i >> 6);
    xs[i >> 6][i & 63] = (grow < nrows) ? src[(size_t)grow * 64 + (i & 63)] : 0.f;
  }
  __syncthreads();
  #pragma unroll
  for (int p = 0; p < 4; ++p) {
    const int row = p * 4 + rr;
    const int grow = base + row;
    float acc = 0.f;
    #pragma unroll
    for (int c = 0; c < 64; ++c) acc = fmaf(xs[row][c], Wl[c * 65 + cc], acc);
    if (grow < nrows) dst[(size_t)grow * 64 + cc] = acc * scale;
  }
}

// ---------------------------------------------------------------------------
// CROSS attention via MFMA (flash-lite, no max subtraction — logits bounded).
// grid (47, NH, B), block 256 (4 waves); wave owns 16 q-rows (block: 64).
// Per 16-key tile: S = mfma(Q, K^T); P = exp(S) (masked >=750); P routed
// C-layout -> A-layout via wave-private padded LDS tile; O += mfma(P, V).
// K: [750][18] f16 (padded rows); V^T: [16][754] f16; Pt: per-wave [16][18].
// LDS 53,432 B -> 3 blocks/CU. Z accumulated per-lane, group-reduced.
// ---------------------------------------------------------------------------
__global__ __launch_bounds__(256) void cross_attn_kernel(
    const float* __restrict__ qp, const float* __restrict__ kp,
    const float* __restrict__ vp, float* __restrict__ ao)
{
  extern __shared__ char smem[];
  unsigned short* Kl = (unsigned short*)smem;       // [750][18]
  unsigned short* Vt = Kl + 750 * 18;               // [16][754]
  unsigned short* Pt = Vt + 16 * 754;               // [4 waves][16][18]

  const int t = threadIdx.x;
  const int h = blockIdx.y, b = blockIdx.z;
  const float* kslab = kp + (size_t)(b * LK) * 64 + h * 16;
  const float* vslab = vp + (size_t)(b * LK) * 64 + h * 16;

  // stage K (row-major f16, pitch 18) and V transposed ([d][key])
  for (int k = t; k < LK; k += 256) {
    const float4* ks = (const float4*)(kslab + (size_t)k * 64);
    const float4* vs = (const float4*)(vslab + (size_t)k * 64);
    unsigned int* kr = (unsigned int*)(Kl + k * 18);
    #pragma unroll
    for (int q4 = 0; q4 < 4; ++q4) {
      float4 a = ks[q4], v = vs[q4];
      kr[q4 * 2]     = packh2(a.x, a.y);
      kr[q4 * 2 + 1] = packh2(a.z, a.w);
      Vt[(q4 * 4 + 0) * 754 + k] = f2h(v.x);
      Vt[(q4 * 4 + 1) * 754 + k] = f2h(v.y);
      Vt[(q4 * 4 + 2) * 754 + k] = f2h(v.z);
      Vt[(q4 * 4 + 3) * 754 + k] = f2h(v.w);
    }
  }
  // zero V pad keys 750..751 (P is masked there, but 0*NaN would poison O)
  if (t < 32) Vt[(t & 15) * 754 + 750 + (t >> 4)] = 0;
  __syncthreads();

  const int wave = t >> 6, lane = t & 63;
  const int col = lane & 15, quad = lane >> 4;
  const int qbase = blockIdx.x * 64 + wave * 16;
  unsigned short* Pt_w = Pt + wave * 288;   // [16][18]

  // Q A-fragment: A[m=col][k=quad*4+j], constant across tiles
  int qrow = qbase + col; if (qrow >= LQ) qrow = LQ - 1;
  const float* qptr = qp + ((size_t)(b * LQ + qrow)) * 64 + h * 16 + quad * 4;
  half4_t aQ;
  {
    unsigned long long v = ((unsigned long long)packh2(qptr[2], qptr[3]) << 32)
                         | packh2(qptr[0], qptr[1]);
    __builtin_memcpy(&aQ, &v, 8);
  }

  f32x4 O = {0.f, 0.f, 0.f, 0.f};
  float Zp[4] = {0.f, 0.f, 0.f, 0.f};
  const f32x4 zeroC = {0.f, 0.f, 0.f, 0.f};

  for (int tile = 0; tile < 47; ++tile) {
    const int key = tile * 16 + col;
    // B-fragment K^T: B[k=quad*4+j][n=col] = K[key=n][k]
    const half4_t bK = h4_from(Kl + key * 18 + quad * 4);
    f32x4 S = MFMA16(aQ, bK, zeroC);
    // exp + mask (C layout: col=lane&15 -> key, row=quad*4+r)
    const bool valid = key < LK;
    float e0 = valid ? __expf(S[0]) : 0.f;
    float e1 = valid ? __expf(S[1]) : 0.f;
    float e2 = valid ? __expf(S[2]) : 0.f;
    float e3 = valid ? __expf(S[3]) : 0.f;
    Zp[0] += e0; Zp[1] += e1; Zp[2] += e2; Zp[3] += e3;
    // C->A transpose through wave-private LDS tile (barrier-free)
    Pt_w[(quad * 4 + 0) * 18 + col] = f2h(e0);
    Pt_w[(quad * 4 + 1) * 18 + col] = f2h(e1);
    Pt_w[(quad * 4 + 2) * 18 + col] = f2h(e2);
    Pt_w[(quad * 4 + 3) * 18 + col] = f2h(e3);
    const half4_t aP = h4_from(Pt_w + col * 18 + quad * 4);
    // B-fragment V: B[k=quad*4+j][n=col] = V[key=tile*16+quad*4+j][d=col]
    const half4_t bV = h4_from(Vt + col * 754 + tile * 16 + quad * 4);
    O = MFMA16(aP, bV, O);
  }

  // reduce Z across the 16-lane col group (rows quad*4+r live there)
  #pragma unroll
  for (int r = 0; r < 4; ++r) {
    float z = Zp[r];
    z += __shfl_xor(z, 1);
    z += __shfl_xor(z, 2);
    z += __shfl_xor(z, 4);
    z += __shfl_xor(z, 8);
    Zp[r] = z;
  }

  #pragma unroll
  for (int r = 0; r < 4; ++r) {
    const int orow = qbase + quad * 4 + r;
    if (orow < LQ)
      ao[((size_t)(b * LQ + orow)) * 64 + h * 16 + col] = O[r] / Zp[r];
  }
}

// ---------------------------------------------------------------------------
// AWG attention. grid (375, NH, B), block 256. K packed-f16 uint2 in LDS;
// logits via v_dot2_f32_f16 (recompute path bit-identical). Exact-on-f16K
// top-16 via 3-stage ballot select; V gathered from L2.
// LDS: 24,096 + 1,024 + 768 + 384 = 26,272 B -> 6 blocks/CU.
// ---------------------------------------------------------------------------
__global__ __launch_bounds__(256) void awg_attn_kernel(
    const float* __restrict__ qp, const float* __restrict__ kp,
    const float* __restrict__ vp, float* __restrict__ ao)
{
  extern __shared__ char smem[];
  uint2*          KT2   = (uint2*)smem;                              // [4][PITCH]
  unsigned short* candi = (unsigned short*)(smem + 4 * PITCH * 8);   // [4][2][64]
  float*          cw    = (float*)(smem + 4 * PITCH * 8 + 1024);     // [4][2][24]
  unsigned short* ciw   = (unsigned short*)(smem + 4 * PITCH * 8 + 1024 + 768);

  const int t = threadIdx.x;
  const int h = blockIdx.y, b = blockIdx.z;
  const float* kslab = kp + (size_t)(b * LK) * 64 + h * 16;

  for (int k = t; k < LK; k += 256) {
    const float4* ks = (const float4*)(kslab + (size_t)k * 64);
    #pragma unroll
    for (int q4 = 0; q4 < 4; ++q4) {
      float4 a = ks[q4];
      KT2[q4 * PITCH + k] = make_uint2(packh2(a.x, a.y), packh2(a.z, a.w));
    }
  }
  __syncthreads();

  const int wave = t >> 6, lane = t & 63;
  const unsigned long long below = (1ull << lane) - 1ull;
  unsigned short* ci0 = candi + wave * 128;
  unsigned short* ci1 = ci0 + 64;
  float* cw0 = cw + wave * 48;      float* cw1 = cw0 + 24;
  unsigned short* cio0 = ciw + wave * 48; unsigned short* cio1 = cio0 + 24;

  const int r0 = blockIdx.x * 8 + wave * 2;
  const float* qrow = qp + ((size_t)(b * LQ + r0)) * 64 + h * 16;
  unsigned int qw0[8], qw1[8];   // wave-uniform packed f16 q -> SGPRs
  #pragma unroll
  for (int i = 0; i < 8; ++i) {
    qw0[i] = bcastu(packh2(qrow[2 * i], qrow[2 * i + 1]));
    qw1[i] = bcastu(packh2(qrow[64 + 2 * i], qrow[64 + 2 * i + 1]));
  }

  float lg0[12], lg1[12];
  #pragma unroll
  for (int tt = 0; tt < 12; ++tt) {
    const int k = lane + (tt << 6);
    if (tt < 11 || k < LK) {
      float a0 = 0.f, a1 = 0.f;
      #pragma unroll
      for (int d4 = 0; d4 < 4; ++d4) {
        const uint2 w = KT2[d4 * PITCH + k];
        a0 = dot2(w.x, u2h(qw0[2 * d4]), a0); a0 = dot2(w.y, u2h(qw0[2 * d4 + 1]), a0);
        a1 = dot2(w.x, u2h(qw1[2 * d4]), a1); a1 = dot2(w.y, u2h(qw1[2 * d4 + 1]), a1);
      }
      lg0[tt] = a0; lg1[tt] = a1;
    } else {
      lg0[tt] = -3.0e38f; lg1[tt] = -3.0e38f;
    }
  }

  float fm0 = lg0[0], fm1 = lg1[0];
  #pragma unroll
  for (int tt = 1; tt < 12; ++tt) { fm0 = fmaxf(fm0, lg0[tt]); fm1 = fmaxf(fm1, lg1[tt]); }
  float M0 = fm0, M1 = fm1;
  #pragma unroll
  for (int off = 32; off > 0; off >>= 1) {
    M0 = fmaxf(M0, __shfl_xor(M0, off));
    M1 = fmaxf(M1, __shfl_xor(M1, off));
  }
  const unsigned int head0 = f2sort(fm0), head1 = f2sort(fm1);

  unsigned int L0 = 0u, L1 = 0u;
  #pragma unroll
  for (int bit = 31; bit >= 20; --bit) {
    const unsigned int c0 = L0 | (1u << bit);
    const unsigned int c1 = L1 | (1u << bit);
    if (__popcll(__ballot(head0 >= c0)) >= 16) L0 = c0;
    if (__popcll(__ballot(head1 >= c1)) >= 16) L1 = c1;
  }

  int base0 = 0, base1 = 0;
  #pragma unroll
  for (int tt = 0; tt < 12; ++tt) {
    const int k = lane + (tt << 6);
    const bool p0 = f2sort(lg0[tt]) >= L0;
    const bool p1 = f2sort(lg1[tt]) >= L1;
    const unsigned long long m0 = __ballot(p0);
    const unsigned long long m1 = __ballot(p1);
    if (p0) {
      const int pos = base0 + __popcll(m0 & below);
      if (pos < 64) ci0[pos] = (unsigned short)k;
    }
    if (p1) {
      const int pos = base1 + __popcll(m1 & below);
      if (pos < 64) ci1[pos] = (unsigned short)k;
    }
    base0 += __popcll(m0);
    base1 += __popcll(m1);
  }
  const int C0 = min(base0, 64), C1 = min(base1, 64);

  // recompute candidate logits (bit-identical dot2 order)
  const int k0 = (lane < C0) ? (int)ci0[lane] : 0;
  const int k1 = (lane < C1) ? (int)ci1[lane] : 0;
  float cv0 = 0.f, cv1 = 0.f;
  #pragma unroll
  for (int d4 = 0; d4 < 4; ++d4) {
    const uint2 wa = KT2[d4 * PITCH + k0];
    const uint2 wb = KT2[d4 * PITCH + k1];
    cv0 = dot2(wa.x, u2h(qw0[2 * d4]), cv0); cv0 = dot2(wa.y, u2h(qw0[2 * d4 + 1]), cv0);
    cv1 = dot2(wb.x, u2h(qw1[2 * d4]), cv1); cv1 = dot2(wb.y, u2h(qw1[2 * d4 + 1]), cv1);
  }
  const unsigned int cu0 = (lane < C0) ? f2sort(cv0) : 0u;
  const unsigned int cu1 = (lane < C1) ? f2sort(cv1) : 0u;

  unsigned int T0 = 0u, T1 = 0u;
  #pragma unroll
  for (int bit = 31; bit >= 0; --bit) {
    const unsigned int c0 = T0 | (1u << bit);
    const unsigned int c1 = T1 | (1u << bit);
    if (__popcll(__ballot(cu0 >= c0)) >= 16) T0 = c0;
    if (__popcll(__ballot(cu1 >= c1)) >= 16) T1 = c1;
  }

  const bool w0 = (lane < C0) && (cu0 >= T0);
  const bool w1 = (lane < C1) && (cu1 >= T1);
  const unsigned long long mw0 = __ballot(w0);
  const unsigned long long mw1 = __ballot(w1);
  const int cnt0 = min((int)__popcll(mw0), 24);
  const int cnt1 = min((int)__popcll(mw1), 24);
  if (w0) {
    const int pos = __popcll(mw0 & below);
    if (pos < 24) { cw0[pos] = cv0; cio0[pos] = (unsigned short)k0; }
  }
  if (w1) {
    const int pos = __popcll(mw1 & below);
    if (pos < 24) { cw1[pos] = cv1; cio1[pos] = (unsigned short)k1; }
  }

  const int dd = lane & 15;
  const int rsel = (lane >> 4) & 1;
  const int half = lane >> 5;
  const int cnt = rsel ? cnt1 : cnt0;
  const float* cwr = rsel ? cw1 : cw0;
  const unsigned short* cir = rsel ? cio1 : cio0;
  const float ref = rsel ? M1 : M0;
  const float* vbase = vp + (size_t)(b * LK) * 64 + h * 16 + dd;
  float acc = 0.f, Z = 0.f;
  for (int j = half; j < cnt; j += 2) {
    const float e = __expf(cwr[j] - ref);
    Z += e;
    acc = fmaf(e, vbase[(size_t)cir[j] * 64], acc);
  }
  acc += __shfl_xor(acc, 32);
  Z   += __shfl_xor(Z, 32);
  if (lane < 32)
    ao[((size_t)(b * LQ + r0 + rsel)) * 64 + h * 16 + dd] = acc / Z;
}

// ---------------------------------------------------------------------------
// Fused: x1 = LN(ao@Wo + q); h = relu(x1@W1+b1); x = LN(h@W2+b2 + x1)
// W2 staged in LDS 64x64 chunks. grid 750, 16 rows/block. (r10 verified)
// ---------------------------------------------------------------------------
__global__ __launch_bounds__(256) void cross_ffn_kernel(
    const float* __restrict__ ao, const float* __restrict__ qres,
    const float* __restrict__ Wo,
    const float* __restrict__ g1, const float* __restrict__ b1n,
    const float* __restrict__ W1, const float* __restrict__ bb1,
    const float* __restrict__ W2, const float* __restrict__ bb2,
    const float* __restrict__ g2, const float* __restrict__ b2n,
    float* __restrict__ xout)
{
  __shared__ float Wl[64 * 65];
  __shared__ float xs[16][64];
  __shared__ float hs[16][256];
  const int t = threadIdx.x, rr = t >> 6, cc = t & 63;
  const size_t base = (size_t)blockIdx.x * 16;
  for (int i = t; i < 4096; i += 256) Wl[(i >> 6) * 65 + (i & 63)] = Wo[i];
  for (int i = t; i < 1024; i += 256) xs[i >> 6][i & 63] = ao[base * 64 + i];
  __syncthreads();
  float acc[4];
  #pragma unroll
  for (int p = 0; p < 4; ++p) {
    const int row = p * 4 + rr;
    float a = 0.f;
    #pragma unroll
    for (int c = 0; c < 64; ++c) a = fmaf(xs[row][c], Wl[c * 65 + cc], a);
    acc[p] = a + qres[(base + row) * 64 + cc];
  }
  __syncthreads();
  #pragma unroll
  for (int p = 0; p < 4; ++p) {
    const int row = p * 4 + rr;
    xs[row][cc] = row_ln(acc[p], g1[cc], b1n[cc]);
  }
  __syncthreads();
  {
    float hv[16];
    #pragma unroll
    for (int r = 0; r < 16; ++r) hv[r] = 0.f;
    #pragma unroll 8
    for (int c = 0; c < 64; ++c) {
      const float w = W1[c * 256 + t];
      #pragma unroll
      for (int r = 0; r < 16; ++r) hv[r] = fmaf(xs[r][c], w, hv[r]);
    }
    const float bb = bb1[t];
    #pragma unroll
    for (int r = 0; r < 16; ++r) hs[r][t] = fmaxf(hv[r] + bb, 0.f);
  }
  float acc2[4];
  #pragma unroll
  for (int p = 0; p < 4; ++p) acc2[p] = bb2[cc];
  for (int ch = 0; ch < 4; ++ch) {
    __syncthreads();
    for (int i = t; i < 4096; i += 256)
      Wl[(i >> 6) * 65 + (i & 63)] = W2[(ch * 64 + (i >> 6)) * 64 + (i & 63)];
    __syncthreads();
    #pragma unroll
    for (int p = 0; p < 4; ++p) {
      const int row = p * 4 + rr;
      #pragma unroll
      for (int c = 0; c < 64; ++c)
        acc2[p] = fmaf(hs[row][ch * 64 + c], Wl[c * 65 + cc], acc2[p]);
    }
  }
  #pragma unroll
  for (int p = 0; p < 4; ++p) {
    const int row = p * 4 + rr;
    const float a = acc2[p] + xs[row][cc];
    xout[(base + row) * 64 + cc] = row_ln(a, g2[cc], b2n[cc]);
  }
}

// ---------------------------------------------------------------------------
// MGAN pre (layer 0): qn = LN(x); sg = sigmoid(qn@W1+b1)*(qn@W2+b2);
// qp = (sg@Wq)*0.25. W1/W2 direct from global; Wq staged.
// ---------------------------------------------------------------------------
__global__ __launch_bounds__(256) void mgan_pre_kernel(
    const float* __restrict__ x, const float* __restrict__ lng,
    const float* __restrict__ lnb, const float* __restrict__ W1,
    const float* __restrict__ bb1, const float* __restrict__ W2,
    const float* __restrict__ bb2, const float* __restrict__ Wq,
    float* __restrict__ qn, float* __restrict__ sg, float* __restrict__ qp)
{
  __shared__ float Wl[64 * 65];
  __shared__ float qs[16][64];
  __shared__ float sgs[16][64];
  const int t = threadIdx.x, rr = t >> 6, cc = t & 63;
  const size_t base = (size_t)blockIdx.x * 16;
  for (int i = t; i < 4096; i += 256) Wl[(i >> 6) * 65 + (i & 63)] = Wq[i];
  #pragma unroll
  for (int p = 0; p < 4; ++p) {
    const int row = p * 4 + rr;
    const float v = x[(base + row) * 64 + cc];
    const float qv = row_ln(v, lng[cc], lnb[cc]);
    qn[(base + row) * 64 + cc] = qv;
    qs[row][cc] = qv;
  }
  __syncthreads();
  float d1[4], d2[4];
  #pragma unroll
  for (int p = 0; p < 4; ++p) { d1[p] = bb1[cc]; d2[p] = bb2[cc]; }
  #pragma unroll 4
  for (int c = 0; c < 64; ++c) {
    const float w1 = W1[c * 64 + cc];
    const float w2 = W2[c * 64 + cc];
    #pragma unroll
    for (int p = 0; p < 4; ++p) {
      const float xv = qs[p * 4 + rr][c];
      d1[p] = fmaf(xv, w1, d1[p]);
      d2[p] = fmaf(xv, w2, d2[p]);
    }
  }
  #pragma unroll
  for (int p = 0; p < 4; ++p) {
    const int row = p * 4 + rr;
    const float sv = sigmoidf(d1[p]) * d2[p];
    sg[(base + row) * 64 + cc] = sv;
    sgs[row][cc] = sv;
  }
  __syncthreads();
  #pragma unroll
  for (int p = 0; p < 4; ++p) {
    const int row = p * 4 + rr;
    float a = 0.f;
    #pragma unroll
    for (int c = 0; c < 64; ++c) a = fmaf(sgs[row][c], Wl[c * 65 + cc], a);
    qp[(base + row) * 64 + cc] = a * 0.25f;
  }
}

// ---------------------------------------------------------------------------
// Fused awg_out(layer i) + mgan_pre(layer i+1): x never touches HBM.
// W1/W2 direct from global. grid 750, 16 rows/block.
// ---------------------------------------------------------------------------
__global__ __launch_bounds__(256) void out_pre_kernel(
    const float* __restrict__ ao, const float* __restrict__ sg,
    const float* __restrict__ qn, const float* __restrict__ Wo,
    const float* __restrict__ g_, const float* __restrict__ b_,
    const float* __restrict__ lng, const float* __restrict__ lnb,
    const float* __restrict__ W1, const float* __restrict__ bb1,
    const float* __restrict__ W2, const float* __restrict__ bb2,
    const float* __restrict__ Wq,
    float* __restrict__ qn_out, float* __restrict__ sg_out,
    float* __restrict__ qp_out)
{
  __shared__ float Wl[64 * 65];
  __shared__ float xs[16][64];
  __shared__ float sgs[16][64];
  const int t = threadIdx.x, rr = t >> 6, cc = t & 63;
  const size_t base = (size_t)blockIdx.x * 16;
  for (int i = t; i < 4096; i += 256) Wl[(i >> 6) * 65 + (i & 63)] = Wo[i];
  for (int i = t; i < 1024; i += 256) xs[i >> 6][i & 63] = ao[base * 64 + i];
  __syncthreads();
  float accp[4], sgv[4];
  #pragma unroll
  for (int p = 0; p < 4; ++p) {
    const int row = p * 4 + rr;
    const size_t idx = (base + row) * 64 + cc;
    float a = 0.f;
    #pragma unroll
    for (int c = 0; c < 64; ++c) a = fmaf(xs[row][c], Wl[c * 65 + cc], a);
    sgv[p] = sg[idx];
    accp[p] = a + sgv[p];
  }
  __syncthreads();
  #pragma unroll
  for (int p = 0; p < 4; ++p) {
    const int row = p * 4 + rr;
    const size_t idx = (base + row) * 64 + cc;
    const float awg = row_ln(accp[p], g_[cc], b_[cc]);
    const float xv = qn[idx] + sgv[p] * sigmoidf(awg);
    const float qv = row_ln(xv, lng[cc], lnb[cc]);
    qn_out[idx] = qv;
    xs[row][cc] = qv;
  }
  __syncthreads();
  for (int i = t; i < 4096; i += 256) Wl[(i >> 6) * 65 + (i & 63)] = Wq[i];
  float d1[4], d2[4];
  #pragma unroll
  for (int p = 0; p < 4; ++p) { d1[p] = bb1[cc]; d2[p] = bb2[cc]; }
  #pragma unroll 4
  for (int c = 0; c < 64; ++c) {
    const float w1 = W1[c * 64 + cc];
    const float w2 = W2[c * 64 + cc];
    #pragma unroll
    for (int p = 0; p < 4; ++p) {
      const float xv = xs[p * 4 + rr][c];
      d1[p] = fmaf(xv, w1, d1[p]);
      d2[p] = fmaf(xv, w2, d2[p]);
    }
  }
  __syncthreads();
  #pragma unroll
  for (int p = 0; p < 4; ++p) {
    const int row = p * 4 + rr;
    const size_t idx = (base + row) * 64 + cc;
    const float sv = sigmoidf(d1[p]) * d2[p];
    sg_out[idx] = sv;
    sgs[row][cc] = sv;
  }
  __syncthreads();
  #pragma unroll
  for (int p = 0; p < 4; ++p) {
    const int row = p * 4 + rr;
    float a = 0.f;
    #pragma unroll
    for (int c = 0; c < 64; ++c) a = fmaf(sgs[row][c], Wl[c * 65 + cc], a);
    qp_out[(base + row) * 64 + cc] = a * 0.25f;
  }
}

// ---------------------------------------------------------------------------
// Fused awg_out(layer 1) + head: out = sigmoid(x2 @ fcW + fcb).
// grid 750, 16 rows/block. Output fp32.
// ---------------------------------------------------------------------------
__global__ __launch_bounds__(256) void out_final_kernel(
    const float* __restrict__ ao, const float* __restrict__ sg,
    const float* __restrict__ qn, const float* __restrict__ Wo,
    const float* __restrict__ g_, const float* __restrict__ b_,
    const float* __restrict__ fw, const float* __restrict__ fb,
    float* __restrict__ out)
{
  __shared__ float Wl[64 * 65];
  __shared__ float xs[16][64];
  const int t = threadIdx.x, rr = t >> 6, cc = t & 63;
  const size_t base = (size_t)blockIdx.x * 16;
  for (int i = t; i < 4096; i += 256) Wl[(i >> 6) * 65 + (i & 63)] = Wo[i];
  for (int i = t; i < 1024; i += 256) xs[i >> 6][i & 63] = ao[base * 64 + i];
  __syncthreads();
  #pragma unroll
  for (int p = 0; p < 4; ++p) {
    const int row = p * 4 + rr;
    const size_t idx = (base + row) * 64 + cc;
    float a = 0.f;
    #pragma unroll
    for (int c = 0; c < 64; ++c) a = fmaf(xs[row][c], Wl[c * 65 + cc], a);
    const float sgv = sg[idx];
    a += sgv;
    const float awg = row_ln(a, g_[cc], b_[cc]);
    const float xv = qn[idx] + sgv * sigmoidf(awg);
    float v = xv * fw[cc];
    #pragma unroll
    for (int off = 32; off > 0; off >>= 1) v += __shfl_xor(v, off);
    if (cc == 0) out[base + row] = sigmoidf(v + fb[0]);
  }
}

// ---------------------------------------------------------------------------
extern "C" void kernel_launch(void* const* d_in, const int* in_sizes, int n_in,
                              void* d_out, int out_size, void* d_ws, size_t ws_size,
                              hipStream_t stream) {
  (void)in_sizes; (void)n_in; (void)out_size; (void)ws_size;

  const float* q     = (const float*)d_in[0];
  const float* enc   = (const float*)d_in[1];
  const float* calWq = (const float*)d_in[2];
  const float* calWk = (const float*)d_in[3];
  const float* calWv = (const float*)d_in[4];
  const float* calWo = (const float*)d_in[5];
  const float* ln1g  = (const float*)d_in[6];
  const float* ln1b  = (const float*)d_in[7];
  const float* W1    = (const float*)d_in[8];
  const float* b1v   = (const float*)d_in[9];
  const float* W2    = (const float*)d_in[10];
  const float* b2v   = (const float*)d_in[11];
  const float* ln2g  = (const float*)d_in[12];
  const float* ln2b  = (const float*)d_in[13];
  const float* mlng  = (const float*)d_in[14];
  const float* mlnb  = (const float*)d_in[15];
  const float* mfc1W = (const float*)d_in[16];
  const float* mfc1b = (const float*)d_in[17];
  const float* mfc2W = (const float*)d_in[18];
  const float* mfc2b = (const float*)d_in[19];
  const float* mWq   = (const float*)d_in[20];
  const float* mWk   = (const float*)d_in[21];
  const float* mWv   = (const float*)d_in[22];
  const float* mWo   = (const float*)d_in[23];
  const float* malng = (const float*)d_in[24];
  const float* malnb = (const float*)d_in[25];
  const float* fcW   = (const float*)d_in[26];
  const float* fcb   = (const float*)d_in[27];
  float* out = (float*)d_out;

  float* ws  = (float*)d_ws;
  float* kv  = ws + WS_KV;
  float* qp  = ws + WS_QP;
  float* aob = ws + WS_AO;
  float* qnb = ws + WS_QN;
  float* sgb = ws + WS_SG;
  float* xb  = ws + WS_XB;

  const size_t crossLds = (750 * 18 + 16 * 754 + 4 * 288) * 2;     // 53,432 B
  const size_t awgLds   = 4 * PITCH * 8 + 1024 + 768 + 384;        // 26,272 B

  // 1) all K/V projections + cross q-projection in one dispatch
  kvq_proj_kernel<<<dim3(750, 7), 256, 0, stream>>>(enc, q, calWq, calWk, calWv,
                                                    mWk, mWv, kv, qp);

  // 2) cross attention (MFMA flash-lite) + fused FFN epilogue
  cross_attn_kernel<<<dim3(47, NH_, B_), 256, crossLds, stream>>>(qp, kv, kv + 192000, aob);
  cross_ffn_kernel<<<750, 256, 0, stream>>>(aob, q, calWo, ln1g, ln1b,
                                            W1, b1v, W2, b2v, ln2g, ln2b, xb);

  // 3) MGAN layer 0
  mgan_pre_kernel<<<750, 256, 0, stream>>>(xb, mlng, mlnb, mfc1W, mfc1b,
                                           mfc2W, mfc2b, mWq, qnb, sgb, qp);
  awg_attn_kernel<<<dim3(375, NH_, B_), 256, awgLds, stream>>>(
      qp, kv + 2 * 192000, kv + 3 * 192000, aob);
  out_pre_kernel<<<750, 256, 0, stream>>>(aob, sgb, qnb, mWo, malng, malnb,
                                          mlng + 64, mlnb + 64,
                                          mfc1W + 4096, mfc1b + 64,
                                          mfc2W + 4096, mfc2b + 64,
                                          mWq + 4096, qnb, sgb, qp);

  // 4) MGAN layer 1 + head
  awg_attn_kernel<<<dim3(375, NH_, B_), 256, awgLds, stream>>>(
      qp, kv + 4 * 192000, kv + 5 * 192000, aob);
  out_final_kernel<<<750, 256, 0, stream>>>(aob, sgb, qnb, mWo + 4096,
                                            malng + 64, malnb + 64, fcW, fcb, out);
}